// Round 6
// baseline (2907.443 us; speedup 1.0000x reference)
//
#include <hip/hip_runtime.h>
#include <math.h>

#define NNODES 5000
#define NEDGES 80000
#define NB 8
#define NIN 30
#define K0PAD 32
#define NH 4
#define ND 64
#define NHD 256
#define NT 5
#define NOUT 3
#define ROWS (NB * NNODES) // 40000
#define BNEPS 1e-5f
#define KP 40 // LDS k-stride (shorts), 80B rows -> 2-way bank alias (free)

typedef short shortx8 __attribute__((ext_vector_type(8)));
typedef _Float16 halfx8 __attribute__((ext_vector_type(8)));
typedef _Float16 halfx4 __attribute__((ext_vector_type(4)));
typedef _Float16 halfx2 __attribute__((ext_vector_type(2)));
typedef float floatx4 __attribute__((ext_vector_type(4)));

static __device__ __forceinline__ unsigned short f2h(float f) {
    union { _Float16 h; unsigned short u; } v;
    v.h = (_Float16)f;
    return v.u;
}
static __device__ __forceinline__ float h2f(unsigned short u) {
    union { _Float16 h; unsigned short u; } v;
    v.u = u;
    return (float)v.h;
}

// ---------------- CSR build ----------------

__global__ void count_kernel(const int* __restrict__ dst, int* __restrict__ counts, int n) {
    int e = blockIdx.x * blockDim.x + threadIdx.x;
    if (e < n) atomicAdd(&counts[dst[e]], 1);
}

__global__ __launch_bounds__(1024) void scan_kernel(const int* __restrict__ counts,
                                                    int* __restrict__ offsets, int n) {
    __shared__ int smem[1024];
    const int CH = 5;
    int tid = threadIdx.x;
    int base = tid * CH;
    int loc[CH];
    int s = 0;
    for (int j = 0; j < CH; ++j) {
        int i = base + j;
        int v = (i < n) ? counts[i] : 0;
        loc[j] = s;
        s += v;
    }
    smem[tid] = s;
    __syncthreads();
    for (int off = 1; off < 1024; off <<= 1) {
        int v = (tid >= off) ? smem[tid - off] : 0;
        __syncthreads();
        smem[tid] += v;
        __syncthreads();
    }
    int excl = smem[tid] - s;
    for (int j = 0; j < CH; ++j) {
        int i = base + j;
        if (i < n) offsets[i] = excl + loc[j];
    }
    if (tid == 1023) offsets[n] = smem[1023];
}

__global__ void fill_kernel(const int* __restrict__ src, const int* __restrict__ dst,
                            const int* __restrict__ offsets, int* __restrict__ cursor,
                            int* __restrict__ csr_src, int n) {
    int e = blockIdx.x * blockDim.x + threadIdx.x;
    if (e >= n) return;
    int d = dst[e];
    int pos = offsets[d] + atomicAdd(&cursor[d], 1);
    csr_src[pos] = src[e];
}

// ---------------- packing ----------------

__global__ void pack_xx_kernel(const float* __restrict__ xx, unsigned short* __restrict__ xx16) {
    int idx = blockIdx.x * blockDim.x + threadIdx.x;
    if (idx >= ROWS * K0PAD) return;
    int g = idx >> 5;
    int k = idx & 31;
    float v = (k < NIN) ? xx[(size_t)g * NIN + k] : 0.0f;
    xx16[idx] = f2h(v);
}

// Wt[n][k] = f16(W[k][n]), zero-padded to Kpad rows
__global__ void packWt_kernel(const float* __restrict__ W, unsigned short* __restrict__ Wt,
                              int Kin, int Kpad) {
    int n = blockIdx.x;
    int k = threadIdx.x;
    if (k < Kpad) {
        float v = (k < Kin) ? W[(size_t)k * NHD + n] : 0.0f;
        Wt[(size_t)n * Kpad + k] = f2h(v);
    }
}

// ---------------- MFMA GEMM + fused BN(prev layer) on A + fused el/er ----------------

__global__ __launch_bounds__(256) void gemm_mfma_kernel(
    const unsigned short* __restrict__ A, const unsigned short* __restrict__ Wt,
    const float* __restrict__ alw, const float* __restrict__ arw,
    const float* __restrict__ sums, const float* __restrict__ gamma,
    const float* __restrict__ beta, int apply_bn,
    unsigned short* __restrict__ C16, float* __restrict__ el, float* __restrict__ er,
    int K) {
    __shared__ __align__(16) short As[64 * KP];
    __shared__ __align__(16) short Bs[256 * KP];
    __shared__ float bn_scale[NHD];
    __shared__ float bn_shift[NHD];
    int tid = threadIdx.x;
    if (apply_bn) {
        int c = tid;
        const float invn = 1.0f / (float)ROWS;
        float mu = sums[c] * invn;
        float var = sums[NHD + c] * invn - mu * mu;
        float sc = rsqrtf(var + BNEPS) * gamma[c];
        bn_scale[c] = sc;
        bn_shift[c] = beta[c] - mu * sc;
    }
    __syncthreads();

    int wave = tid >> 6; // head
    int lane = tid & 63;
    int c = lane & 15;
    int quad = lane >> 4;
    int row0 = blockIdx.x * 64;

    floatx4 acc[4][4];
#pragma unroll
    for (int mt = 0; mt < 4; ++mt)
#pragma unroll
        for (int nt = 0; nt < 4; ++nt) acc[mt][nt] = (floatx4){0.f, 0.f, 0.f, 0.f};

    int r = tid >> 2;
    int seg = tid & 3;
    for (int k0 = 0; k0 < K; k0 += 32) {
        // stage A tile 64x32 (+ fused BN + leakyrelu)
        {
            shortx8 v = *(const shortx8*)(A + (size_t)(row0 + r) * K + k0 + seg * 8);
            if (apply_bn) {
                halfx8 hv = *(halfx8*)&v;
                int kg = k0 + seg * 8;
#pragma unroll
                for (int j = 0; j < 8; ++j) {
                    float x = (float)hv[j];
                    x = fmaf(x, bn_scale[kg + j], bn_shift[kg + j]);
                    x = (x > 0.0f) ? x : 0.01f * x;
                    hv[j] = (_Float16)x;
                }
                v = *(shortx8*)&hv;
            }
            *(shortx8*)(&As[r * KP + seg * 8]) = v;
        }
        // stage B tile 256x32 (Wt is [256][K], k contiguous)
#pragma unroll
        for (int it = 0; it < 4; ++it) {
            int n = it * 64 + r;
            shortx8 v = *(const shortx8*)(Wt + (size_t)n * K + k0 + seg * 8);
            *(shortx8*)(&Bs[n * KP + seg * 8]) = v;
        }
        __syncthreads();
        halfx8 a[4], b[4];
#pragma unroll
        for (int mt = 0; mt < 4; ++mt)
            a[mt] = *(const halfx8*)(&As[(mt * 16 + c) * KP + quad * 8]);
#pragma unroll
        for (int nt = 0; nt < 4; ++nt)
            b[nt] = *(const halfx8*)(&Bs[(wave * 64 + nt * 16 + c) * KP + quad * 8]);
#pragma unroll
        for (int mt = 0; mt < 4; ++mt)
#pragma unroll
            for (int nt = 0; nt < 4; ++nt)
                acc[mt][nt] = __builtin_amdgcn_mfma_f32_16x16x32_f16(a[mt], b[nt],
                                                                     acc[mt][nt], 0, 0, 0);
        __syncthreads();
    }

    // epilogue: store f16 C + fused el/er
    float alv[4], arv[4];
#pragma unroll
    for (int nt = 0; nt < 4; ++nt) {
        alv[nt] = alw[wave * 64 + nt * 16 + c];
        arv[nt] = arw[wave * 64 + nt * 16 + c];
    }
#pragma unroll
    for (int mt = 0; mt < 4; ++mt) {
#pragma unroll
        for (int rr = 0; rr < 4; ++rr) {
            int row = row0 + mt * 16 + quad * 4 + rr;
            float pl = 0.0f, pr = 0.0f;
#pragma unroll
            for (int nt = 0; nt < 4; ++nt) {
                float v = acc[mt][nt][rr];
                C16[(size_t)row * NHD + wave * 64 + nt * 16 + c] = f2h(v);
                pl += v * alv[nt];
                pr += v * arv[nt];
            }
#pragma unroll
            for (int o = 1; o < 16; o <<= 1) {
                pl += __shfl_xor(pl, o);
                pr += __shfl_xor(pr, o);
            }
            if (c == mt * 4 + rr) {
                el[(size_t)row * NH + wave] = pl;
                er[(size_t)row * NH + wave] = pr;
            }
        }
    }
}

// ---------------- edge softmax + aggregate (register broadcast, no LDS/barriers) ----------------
// Block = 256 thr = 8 half-waves; half-wave (32 lanes) = (node, head).
// 2 nodes/block. Lane i holds edge i's (src, weight) in registers; gather
// broadcasts via __shfl(.., j, 32). Fast path deg<=64; fallback 3-pass beyond.
// Block 0 also zeroes sums[] (safe: prior gemm consumed it, bnreduce refills after).

__global__ __launch_bounds__(256) void attn_kernel(const unsigned short* __restrict__ h16,
                                                   const float* __restrict__ el,
                                                   const float* __restrict__ er,
                                                   const int* __restrict__ offsets,
                                                   const int* __restrict__ csr_src,
                                                   unsigned short* __restrict__ out16,
                                                   float* __restrict__ sums) {
    int p = blockIdx.x;
    int tid = threadIdx.x;
    if (p == 0) { // 256 threads zero all 512 entries (R5 bug: only 256 were zeroed)
        sums[tid] = 0.0f;
        sums[tid + NHD] = 0.0f;
    }
    int b = p & 7;
    int n2 = p >> 3; // 0..2499
    int hw = tid >> 5;      // half-wave 0..7
    int nn = hw >> 2;       // node within pair
    int head = hw & 3;
    int l32 = tid & 31;
    int n = n2 * 2 + nn;
    int g = b * NNODES + n;
    int start = offsets[n];
    int end = offsets[n + 1];
    int deg = end - start;
    const float* elb = el + (size_t)b * NNODES * NH;
    float er_nh = er[(size_t)g * NH + head];
    const unsigned short* hb = h16 + (size_t)b * NNODES * NHD + head * ND + l32 * 2;

    if (deg <= 64) {
        // lane i holds edge i (and edge i+32) src + weight in registers
        int s0 = 0, s1 = 0;
        float e0 = -INFINITY, e1 = -INFINITY;
        if (l32 < deg) {
            s0 = csr_src[start + l32];
            float e = elb[s0 * NH + head] + er_nh;
            e0 = (e > 0.0f) ? e : 0.2f * e;
        }
        if (l32 + 32 < deg) {
            s1 = csr_src[start + 32 + l32];
            float e = elb[s1 * NH + head] + er_nh;
            e1 = (e > 0.0f) ? e : 0.2f * e;
        }
        float mx = fmaxf(e0, e1);
#pragma unroll
        for (int o = 16; o; o >>= 1) mx = fmaxf(mx, __shfl_xor(mx, o));
        float w0 = __expf(e0 - mx);
        float w1 = __expf(e1 - mx);
        float sm = w0 + w1;
#pragma unroll
        for (int o = 16; o; o >>= 1) sm += __shfl_xor(sm, o);

        float ax0 = 0.f, ay0 = 0.f, ax1 = 0.f, ay1 = 0.f;
        int j = 0;
        int dlo = (deg < 32) ? deg : 32;
        for (; j + 2 <= dlo; j += 2) {
            int sa = __shfl(s0, j, 32);
            int sb = __shfl(s0, j + 1, 32);
            float wa = __shfl(w0, j, 32);
            float wb = __shfl(w0, j + 1, 32);
            halfx2 ha = *(const halfx2*)(hb + (size_t)sa * NHD);
            halfx2 hc = *(const halfx2*)(hb + (size_t)sb * NHD);
            ax0 += wa * (float)ha.x;
            ay0 += wa * (float)ha.y;
            ax1 += wb * (float)hc.x;
            ay1 += wb * (float)hc.y;
        }
        if (j < dlo) {
            int sa = __shfl(s0, j, 32);
            float wa = __shfl(w0, j, 32);
            halfx2 ha = *(const halfx2*)(hb + (size_t)sa * NHD);
            ax0 += wa * (float)ha.x;
            ay0 += wa * (float)ha.y;
        }
        for (j = 32; j + 2 <= deg; j += 2) {
            int sa = __shfl(s1, j - 32, 32);
            int sb = __shfl(s1, j - 31, 32);
            float wa = __shfl(w1, j - 32, 32);
            float wb = __shfl(w1, j - 31, 32);
            halfx2 ha = *(const halfx2*)(hb + (size_t)sa * NHD);
            halfx2 hc = *(const halfx2*)(hb + (size_t)sb * NHD);
            ax0 += wa * (float)ha.x;
            ay0 += wa * (float)ha.y;
            ax1 += wb * (float)hc.x;
            ay1 += wb * (float)hc.y;
        }
        if (j < deg && deg > 32) {
            int sa = __shfl(s1, j - 32, 32);
            float wa = __shfl(w1, j - 32, 32);
            halfx2 ha = *(const halfx2*)(hb + (size_t)sa * NHD);
            ax0 += wa * (float)ha.x;
            ay0 += wa * (float)ha.y;
        }
        float inv = (deg > 0) ? 1.0f / sm : 0.0f;
        halfx2 o2;
        o2.x = (_Float16)((ax0 + ax1) * inv);
        o2.y = (_Float16)((ay0 + ay1) * inv);
        *(halfx2*)(out16 + (size_t)g * NHD + head * ND + l32 * 2) = o2;
    } else {
        // fallback: 3-pass recompute from CSR (deg > 64, rare)
        float mx = -INFINITY;
        for (int i = start + l32; i < end; i += 32) {
            float e = elb[csr_src[i] * NH + head] + er_nh;
            e = (e > 0.0f) ? e : 0.2f * e;
            mx = fmaxf(mx, e);
        }
#pragma unroll
        for (int o = 16; o; o >>= 1) mx = fmaxf(mx, __shfl_xor(mx, o));
        float sm = 0.0f;
        for (int i = start + l32; i < end; i += 32) {
            float e = elb[csr_src[i] * NH + head] + er_nh;
            e = (e > 0.0f) ? e : 0.2f * e;
            sm += __expf(e - mx);
        }
#pragma unroll
        for (int o = 16; o; o >>= 1) sm += __shfl_xor(sm, o);
        float ax = 0.f, ay = 0.f;
        for (int i = start; i < end; ++i) {
            int s = csr_src[i];
            float e = elb[s * NH + head] + er_nh;
            e = (e > 0.0f) ? e : 0.2f * e;
            float w = __expf(e - mx);
            halfx2 hv = *(const halfx2*)(hb + (size_t)s * NHD);
            ax += w * (float)hv.x;
            ay += w * (float)hv.y;
        }
        float inv = (deg > 0) ? 1.0f / sm : 0.0f;
        halfx2 o2;
        o2.x = (_Float16)(ax * inv);
        o2.y = (_Float16)(ay * inv);
        *(halfx2*)(out16 + (size_t)g * NHD + head * ND + l32 * 2) = o2;
    }
}

// ---------------- BatchNorm stats from f16 activations ----------------
// thread -> channel pair (halfx2); 1280 row-streams; 4 atomics/thread.

__global__ __launch_bounds__(256) void bnreduce_kernel(const unsigned short* __restrict__ x16,
                                                       float* __restrict__ sums) {
    int tid = threadIdx.x;
    int c2 = (tid & 127) * 2;
    int rhalf = tid >> 7;
    float sx = 0.f, sx2 = 0.f, sy = 0.f, sy2 = 0.f;
    for (int row = blockIdx.x * 2 + rhalf; row < ROWS; row += 1280) {
        halfx2 hv = *(const halfx2*)(x16 + (size_t)row * NHD + c2);
        float vx = (float)hv.x, vy = (float)hv.y;
        sx += vx;
        sx2 += vx * vx;
        sy += vy;
        sy2 += vy * vy;
    }
    atomicAdd(&sums[c2], sx);
    atomicAdd(&sums[c2 + 1], sy);
    atomicAdd(&sums[NHD + c2], sx2);
    atomicAdd(&sums[NHD + c2 + 1], sy2);
}

// ---------------- output head (inline BN+lrelu) + f16 window shift ----------------

__global__ __launch_bounds__(256) void headout_kernel(const unsigned short* __restrict__ x16,
                                                      const float* __restrict__ sums,
                                                      const float* __restrict__ gamma,
                                                      const float* __restrict__ beta,
                                                      const float* __restrict__ Wout,
                                                      const float* __restrict__ bout,
                                                      float* __restrict__ out,
                                                      unsigned short* __restrict__ xx16, int t) {
    int wave = threadIdx.x >> 6;
    int lane = threadIdx.x & 63;
    int g = blockIdx.x * 4 + wave;
    int c0 = lane * 4;
    halfx4 hv = *(const halfx4*)(x16 + (size_t)g * NHD + c0);
    const float invn = 1.0f / (float)ROWS;
    float vv[4];
#pragma unroll
    for (int j = 0; j < 4; ++j) {
        int c = c0 + j;
        float mu = sums[c] * invn;
        float var = sums[NHD + c] * invn - mu * mu;
        float sc = rsqrtf(var + BNEPS) * gamma[c];
        float x = fmaf((float)hv[j], sc, beta[c] - mu * sc);
        vv[j] = (x > 0.0f) ? x : 0.01f * x;
    }
    float r0 = vv[0] * Wout[(c0 + 0) * NOUT + 0] + vv[1] * Wout[(c0 + 1) * NOUT + 0] +
               vv[2] * Wout[(c0 + 2) * NOUT + 0] + vv[3] * Wout[(c0 + 3) * NOUT + 0];
    float r1 = vv[0] * Wout[(c0 + 0) * NOUT + 1] + vv[1] * Wout[(c0 + 1) * NOUT + 1] +
               vv[2] * Wout[(c0 + 2) * NOUT + 1] + vv[3] * Wout[(c0 + 3) * NOUT + 1];
    float r2 = vv[0] * Wout[(c0 + 0) * NOUT + 2] + vv[1] * Wout[(c0 + 1) * NOUT + 2] +
               vv[2] * Wout[(c0 + 2) * NOUT + 2] + vv[3] * Wout[(c0 + 3) * NOUT + 2];
#pragma unroll
    for (int o = 32; o; o >>= 1) {
        r0 += __shfl_xor(r0, o);
        r1 += __shfl_xor(r1, o);
        r2 += __shfl_xor(r2, o);
    }
    float o0 = r0 + bout[0], o1 = r1 + bout[1], o2 = r2 + bout[2];
    if (lane == 0) {
        float* op = out + ((size_t)g * NT + t) * NOUT;
        op[0] = o0;
        op[1] = o1;
        op[2] = o2;
    }
    // shift f16 input window: new[0:27] = old[3:30]; new[27:30] = out
    float oldv = (lane < NIN) ? h2f(xx16[(size_t)g * K0PAD + lane]) : 0.0f;
    float shifted = __shfl(oldv, lane + 3);
    float newv = (lane < 27) ? shifted : (lane == 27 ? o0 : (lane == 28 ? o1 : o2));
    if (lane < NIN) xx16[(size_t)g * K0PAD + lane] = f2h(newv);
}

// ---------------- launch ----------------

extern "C" void kernel_launch(void* const* d_in, const int* in_sizes, int n_in,
                              void* d_out, int out_size, void* d_ws, size_t ws_size,
                              hipStream_t stream) {
    const float* xx = (const float*)d_in[0];
    const int* src = (const int*)d_in[1];
    const int* dst = (const int*)d_in[2];
    const float* W[4] = {(const float*)d_in[3], (const float*)d_in[8],
                         (const float*)d_in[13], (const float*)d_in[18]};
    const float* al[4] = {(const float*)d_in[4], (const float*)d_in[9],
                          (const float*)d_in[14], (const float*)d_in[19]};
    const float* ar[4] = {(const float*)d_in[5], (const float*)d_in[10],
                          (const float*)d_in[15], (const float*)d_in[20]};
    const float* gamma[4] = {(const float*)d_in[6], (const float*)d_in[11],
                             (const float*)d_in[16], (const float*)d_in[21]};
    const float* beta[4] = {(const float*)d_in[7], (const float*)d_in[12],
                            (const float*)d_in[17], (const float*)d_in[22]};
    const float* W_out = (const float*)d_in[23];
    const float* b_out = (const float*)d_in[24];
    float* out = (float*)d_out;

    // workspace carve
    float* wsf = (float*)d_ws;
    float* el = wsf;                                        // ROWS*NH
    float* er = el + (size_t)ROWS * NH;                     // ROWS*NH
    float* sums = er + (size_t)ROWS * NH;                   // 2*NHD
    unsigned short* h16 = (unsigned short*)(sums + 2 * NHD);  // ROWS*NHD (gemm out)
    unsigned short* act16 = h16 + (size_t)ROWS * NHD;       // ROWS*NHD (attn out)
    unsigned short* xx16 = act16 + (size_t)ROWS * NHD;      // ROWS*K0PAD
    unsigned short* Wt0 = xx16 + (size_t)ROWS * K0PAD;      // 256*K0PAD
    unsigned short* Wt1 = Wt0 + 256 * K0PAD;                // 256*256
    unsigned short* Wt2 = Wt1 + 256 * NHD;
    unsigned short* Wt3 = Wt2 + 256 * NHD;
    int* counts = (int*)(Wt3 + 256 * NHD);                  // NNODES
    int* offsets = counts + NNODES;                         // NNODES+1 (+pad)
    int* cursor = offsets + NNODES + 8;                     // NNODES
    int* csr_src = cursor + NNODES;                         // NEDGES
    const unsigned short* Wt[4] = {Wt0, Wt1, Wt2, Wt3};

    // ---- CSR build + packing (once per launch) ----
    hipMemsetAsync(counts, 0, NNODES * sizeof(int), stream);
    count_kernel<<<(NEDGES + 255) / 256, 256, 0, stream>>>(dst, counts, NEDGES);
    scan_kernel<<<1, 1024, 0, stream>>>(counts, offsets, NNODES);
    hipMemsetAsync(cursor, 0, NNODES * sizeof(int), stream);
    fill_kernel<<<(NEDGES + 255) / 256, 256, 0, stream>>>(src, dst, offsets, cursor,
                                                          csr_src, NEDGES);
    pack_xx_kernel<<<(ROWS * K0PAD + 255) / 256, 256, 0, stream>>>(xx, xx16);
    packWt_kernel<<<256, 256, 0, stream>>>(W[0], Wt0, NIN, K0PAD);
    packWt_kernel<<<256, 256, 0, stream>>>(W[1], Wt1, NHD, NHD);
    packWt_kernel<<<256, 256, 0, stream>>>(W[2], Wt2, NHD, NHD);
    packWt_kernel<<<256, 256, 0, stream>>>(W[3], Wt3, NHD, NHD);

    for (int t = 0; t < NT; ++t) {
        for (int l = 0; l < 4; ++l) {
            const unsigned short* A16 = (l == 0) ? xx16 : act16;
            int K = (l == 0) ? K0PAD : NHD;
            int apply_bn = (l > 0) ? 1 : 0;
            const float* pg = gamma[(l > 0) ? l - 1 : 0];
            const float* pb = beta[(l > 0) ? l - 1 : 0];
            gemm_mfma_kernel<<<ROWS / 64, 256, 0, stream>>>(A16, Wt[l], al[l], ar[l],
                                                            sums, pg, pb, apply_bn,
                                                            h16, el, er, K);
            attn_kernel<<<ROWS / 2, 256, 0, stream>>>(h16, el, er, offsets, csr_src,
                                                      act16, sums);
            bnreduce_kernel<<<640, 256, 0, stream>>>(act16, sums);
        }
        headout_kernel<<<ROWS / 4, 256, 0, stream>>>(act16, sums, gamma[3], beta[3],
                                                     W_out, b_out, out, xx16, t);
    }
}

// Round 7
// 1924.234 us; speedup vs baseline: 1.5110x; 1.5110x over previous
//
#include <hip/hip_runtime.h>
#include <math.h>

#define NNODES 5000
#define NEDGES 80000
#define NB 8
#define NIN 30
#define K0PAD 32
#define NH 4
#define ND 64
#define NHD 256
#define NT 5
#define NOUT 3
#define ROWS (NB * NNODES) // 40000
#define BNEPS 1e-5f
#define KP 40 // LDS k-stride (shorts), 80B rows -> 2-way bank alias (free)
#define NREP 8 // sums[] replicas (atomic-contention spread)

typedef short shortx8 __attribute__((ext_vector_type(8)));
typedef _Float16 halfx8 __attribute__((ext_vector_type(8)));
typedef _Float16 halfx4 __attribute__((ext_vector_type(4)));
typedef _Float16 halfx2 __attribute__((ext_vector_type(2)));
typedef float floatx4 __attribute__((ext_vector_type(4)));

static __device__ __forceinline__ unsigned short f2h(float f) {
    union { _Float16 h; unsigned short u; } v;
    v.h = (_Float16)f;
    return v.u;
}
static __device__ __forceinline__ float h2f(unsigned short u) {
    union { _Float16 h; unsigned short u; } v;
    v.u = u;
    return (float)v.h;
}

// ---------------- CSR build ----------------

__global__ void count_kernel(const int* __restrict__ dst, int* __restrict__ counts, int n) {
    int e = blockIdx.x * blockDim.x + threadIdx.x;
    if (e < n) atomicAdd(&counts[dst[e]], 1);
}

__global__ __launch_bounds__(1024) void scan_kernel(const int* __restrict__ counts,
                                                    int* __restrict__ offsets, int n) {
    __shared__ int smem[1024];
    const int CH = 5;
    int tid = threadIdx.x;
    int base = tid * CH;
    int loc[CH];
    int s = 0;
    for (int j = 0; j < CH; ++j) {
        int i = base + j;
        int v = (i < n) ? counts[i] : 0;
        loc[j] = s;
        s += v;
    }
    smem[tid] = s;
    __syncthreads();
    for (int off = 1; off < 1024; off <<= 1) {
        int v = (tid >= off) ? smem[tid - off] : 0;
        __syncthreads();
        smem[tid] += v;
        __syncthreads();
    }
    int excl = smem[tid] - s;
    for (int j = 0; j < CH; ++j) {
        int i = base + j;
        if (i < n) offsets[i] = excl + loc[j];
    }
    if (tid == 1023) offsets[n] = smem[1023];
}

__global__ void fill_kernel(const int* __restrict__ src, const int* __restrict__ dst,
                            const int* __restrict__ offsets, int* __restrict__ cursor,
                            int* __restrict__ csr_src, int n) {
    int e = blockIdx.x * blockDim.x + threadIdx.x;
    if (e >= n) return;
    int d = dst[e];
    int pos = offsets[d] + atomicAdd(&cursor[d], 1);
    csr_src[pos] = src[e];
}

// ---------------- packing ----------------

__global__ void pack_xx_kernel(const float* __restrict__ xx, unsigned short* __restrict__ xx16) {
    int idx = blockIdx.x * blockDim.x + threadIdx.x;
    if (idx >= ROWS * K0PAD) return;
    int g = idx >> 5;
    int k = idx & 31;
    float v = (k < NIN) ? xx[(size_t)g * NIN + k] : 0.0f;
    xx16[idx] = f2h(v);
}

// Wt[n][k] = f16(W[k][n]), zero-padded to Kpad rows
__global__ void packWt_kernel(const float* __restrict__ W, unsigned short* __restrict__ Wt,
                              int Kin, int Kpad) {
    int n = blockIdx.x;
    int k = threadIdx.x;
    if (k < Kpad) {
        float v = (k < Kin) ? W[(size_t)k * NHD + n] : 0.0f;
        Wt[(size_t)n * Kpad + k] = f2h(v);
    }
}

// ---------------- MFMA GEMM + fused BN(prev layer) on A + fused el/er ----------------

__global__ __launch_bounds__(256) void gemm_mfma_kernel(
    const unsigned short* __restrict__ A, const unsigned short* __restrict__ Wt,
    const float* __restrict__ alw, const float* __restrict__ arw,
    const float* __restrict__ sums, const float* __restrict__ gamma,
    const float* __restrict__ beta, int apply_bn,
    unsigned short* __restrict__ C16, float* __restrict__ el, float* __restrict__ er,
    int K) {
    __shared__ __align__(16) short As[64 * KP];
    __shared__ __align__(16) short Bs[256 * KP];
    __shared__ float bn_scale[NHD];
    __shared__ float bn_shift[NHD];
    int tid = threadIdx.x;
    if (apply_bn) {
        int c = tid;
        float s = 0.0f, s2 = 0.0f;
#pragma unroll
        for (int r2 = 0; r2 < NREP; ++r2) {
            s += sums[r2 * 2 * NHD + c];
            s2 += sums[r2 * 2 * NHD + NHD + c];
        }
        const float invn = 1.0f / (float)ROWS;
        float mu = s * invn;
        float var = s2 * invn - mu * mu;
        float sc = rsqrtf(var + BNEPS) * gamma[c];
        bn_scale[c] = sc;
        bn_shift[c] = beta[c] - mu * sc;
    }
    __syncthreads();

    int wave = tid >> 6; // head
    int lane = tid & 63;
    int c = lane & 15;
    int quad = lane >> 4;
    int row0 = blockIdx.x * 64;

    floatx4 acc[4][4];
#pragma unroll
    for (int mt = 0; mt < 4; ++mt)
#pragma unroll
        for (int nt = 0; nt < 4; ++nt) acc[mt][nt] = (floatx4){0.f, 0.f, 0.f, 0.f};

    int r = tid >> 2;
    int seg = tid & 3;
    for (int k0 = 0; k0 < K; k0 += 32) {
        // stage A tile 64x32 (+ fused BN + leakyrelu)
        {
            shortx8 v = *(const shortx8*)(A + (size_t)(row0 + r) * K + k0 + seg * 8);
            if (apply_bn) {
                halfx8 hv = *(halfx8*)&v;
                int kg = k0 + seg * 8;
#pragma unroll
                for (int j = 0; j < 8; ++j) {
                    float x = (float)hv[j];
                    x = fmaf(x, bn_scale[kg + j], bn_shift[kg + j]);
                    x = (x > 0.0f) ? x : 0.01f * x;
                    hv[j] = (_Float16)x;
                }
                v = *(shortx8*)&hv;
            }
            *(shortx8*)(&As[r * KP + seg * 8]) = v;
        }
        // stage B tile 256x32 (Wt is [256][K], k contiguous)
#pragma unroll
        for (int it = 0; it < 4; ++it) {
            int n = it * 64 + r;
            shortx8 v = *(const shortx8*)(Wt + (size_t)n * K + k0 + seg * 8);
            *(shortx8*)(&Bs[n * KP + seg * 8]) = v;
        }
        __syncthreads();
        halfx8 a[4], b[4];
#pragma unroll
        for (int mt = 0; mt < 4; ++mt)
            a[mt] = *(const halfx8*)(&As[(mt * 16 + c) * KP + quad * 8]);
#pragma unroll
        for (int nt = 0; nt < 4; ++nt)
            b[nt] = *(const halfx8*)(&Bs[(wave * 64 + nt * 16 + c) * KP + quad * 8]);
#pragma unroll
        for (int mt = 0; mt < 4; ++mt)
#pragma unroll
            for (int nt = 0; nt < 4; ++nt)
                acc[mt][nt] = __builtin_amdgcn_mfma_f32_16x16x32_f16(a[mt], b[nt],
                                                                     acc[mt][nt], 0, 0, 0);
        __syncthreads();
    }

    // epilogue: store f16 C + fused el/er
    float alv[4], arv[4];
#pragma unroll
    for (int nt = 0; nt < 4; ++nt) {
        alv[nt] = alw[wave * 64 + nt * 16 + c];
        arv[nt] = arw[wave * 64 + nt * 16 + c];
    }
#pragma unroll
    for (int mt = 0; mt < 4; ++mt) {
#pragma unroll
        for (int rr = 0; rr < 4; ++rr) {
            int row = row0 + mt * 16 + quad * 4 + rr;
            float pl = 0.0f, pr = 0.0f;
#pragma unroll
            for (int nt = 0; nt < 4; ++nt) {
                float v = acc[mt][nt][rr];
                C16[(size_t)row * NHD + wave * 64 + nt * 16 + c] = f2h(v);
                pl += v * alv[nt];
                pr += v * arv[nt];
            }
#pragma unroll
            for (int o = 1; o < 16; o <<= 1) {
                pl += __shfl_xor(pl, o);
                pr += __shfl_xor(pr, o);
            }
            if (c == mt * 4 + rr) {
                el[(size_t)row * NH + wave] = pl;
                er[(size_t)row * NH + wave] = pr;
            }
        }
    }
}

// ---------------- edge softmax + aggregate (register broadcast, no LDS/barriers) ----------------
// Block = 256 thr = 8 half-waves; half-wave (32 lanes) = (node, head).
// 2 nodes/block. Lane i holds edge i's (src, weight) in registers; gather
// broadcasts via __shfl(.., j, 32). Fast path deg<=64; fallback 3-pass beyond.
// Block 0 zeroes all NREP sums replicas (prior gemm consumed them; bnreduce refills after).

__global__ __launch_bounds__(256) void attn_kernel(const unsigned short* __restrict__ h16,
                                                   const float* __restrict__ el,
                                                   const float* __restrict__ er,
                                                   const int* __restrict__ offsets,
                                                   const int* __restrict__ csr_src,
                                                   unsigned short* __restrict__ out16,
                                                   float* __restrict__ sums) {
    int p = blockIdx.x;
    int tid = threadIdx.x;
    if (p == 0) {
        for (int i = tid; i < NREP * 2 * NHD; i += 256) sums[i] = 0.0f;
    }
    int b = p & 7;
    int n2 = p >> 3; // 0..2499
    int hw = tid >> 5;      // half-wave 0..7
    int nn = hw >> 2;       // node within pair
    int head = hw & 3;
    int l32 = tid & 31;
    int n = n2 * 2 + nn;
    int g = b * NNODES + n;
    int start = offsets[n];
    int end = offsets[n + 1];
    int deg = end - start;
    const float* elb = el + (size_t)b * NNODES * NH;
    float er_nh = er[(size_t)g * NH + head];
    const unsigned short* hb = h16 + (size_t)b * NNODES * NHD + head * ND + l32 * 2;

    if (deg <= 64) {
        // lane i holds edge i (and edge i+32) src + weight in registers
        int s0 = 0, s1 = 0;
        float e0 = -INFINITY, e1 = -INFINITY;
        if (l32 < deg) {
            s0 = csr_src[start + l32];
            float e = elb[s0 * NH + head] + er_nh;
            e0 = (e > 0.0f) ? e : 0.2f * e;
        }
        if (l32 + 32 < deg) {
            s1 = csr_src[start + 32 + l32];
            float e = elb[s1 * NH + head] + er_nh;
            e1 = (e > 0.0f) ? e : 0.2f * e;
        }
        float mx = fmaxf(e0, e1);
#pragma unroll
        for (int o = 16; o; o >>= 1) mx = fmaxf(mx, __shfl_xor(mx, o));
        float w0 = __expf(e0 - mx);
        float w1 = __expf(e1 - mx);
        float sm = w0 + w1;
#pragma unroll
        for (int o = 16; o; o >>= 1) sm += __shfl_xor(sm, o);

        float ax0 = 0.f, ay0 = 0.f, ax1 = 0.f, ay1 = 0.f;
        int j = 0;
        int dlo = (deg < 32) ? deg : 32;
        for (; j + 2 <= dlo; j += 2) {
            int sa = __shfl(s0, j, 32);
            int sb = __shfl(s0, j + 1, 32);
            float wa = __shfl(w0, j, 32);
            float wb = __shfl(w0, j + 1, 32);
            halfx2 ha = *(const halfx2*)(hb + (size_t)sa * NHD);
            halfx2 hc = *(const halfx2*)(hb + (size_t)sb * NHD);
            ax0 += wa * (float)ha.x;
            ay0 += wa * (float)ha.y;
            ax1 += wb * (float)hc.x;
            ay1 += wb * (float)hc.y;
        }
        if (j < dlo) {
            int sa = __shfl(s0, j, 32);
            float wa = __shfl(w0, j, 32);
            halfx2 ha = *(const halfx2*)(hb + (size_t)sa * NHD);
            ax0 += wa * (float)ha.x;
            ay0 += wa * (float)ha.y;
        }
        for (j = 32; j + 2 <= deg; j += 2) {
            int sa = __shfl(s1, j - 32, 32);
            int sb = __shfl(s1, j - 31, 32);
            float wa = __shfl(w1, j - 32, 32);
            float wb = __shfl(w1, j - 31, 32);
            halfx2 ha = *(const halfx2*)(hb + (size_t)sa * NHD);
            halfx2 hc = *(const halfx2*)(hb + (size_t)sb * NHD);
            ax0 += wa * (float)ha.x;
            ay0 += wa * (float)ha.y;
            ax1 += wb * (float)hc.x;
            ay1 += wb * (float)hc.y;
        }
        if (j < deg && deg > 32) {
            int sa = __shfl(s1, j - 32, 32);
            float wa = __shfl(w1, j - 32, 32);
            halfx2 ha = *(const halfx2*)(hb + (size_t)sa * NHD);
            ax0 += wa * (float)ha.x;
            ay0 += wa * (float)ha.y;
        }
        float inv = (deg > 0) ? 1.0f / sm : 0.0f;
        halfx2 o2;
        o2.x = (_Float16)((ax0 + ax1) * inv);
        o2.y = (_Float16)((ay0 + ay1) * inv);
        *(halfx2*)(out16 + (size_t)g * NHD + head * ND + l32 * 2) = o2;
    } else {
        // fallback: 3-pass recompute from CSR (deg > 64, rare)
        float mx = -INFINITY;
        for (int i = start + l32; i < end; i += 32) {
            float e = elb[csr_src[i] * NH + head] + er_nh;
            e = (e > 0.0f) ? e : 0.2f * e;
            mx = fmaxf(mx, e);
        }
#pragma unroll
        for (int o = 16; o; o >>= 1) mx = fmaxf(mx, __shfl_xor(mx, o));
        float sm = 0.0f;
        for (int i = start + l32; i < end; i += 32) {
            float e = elb[csr_src[i] * NH + head] + er_nh;
            e = (e > 0.0f) ? e : 0.2f * e;
            sm += __expf(e - mx);
        }
#pragma unroll
        for (int o = 16; o; o >>= 1) sm += __shfl_xor(sm, o);
        float ax = 0.f, ay = 0.f;
        for (int i = start; i < end; ++i) {
            int s = csr_src[i];
            float e = elb[s * NH + head] + er_nh;
            e = (e > 0.0f) ? e : 0.2f * e;
            float w = __expf(e - mx);
            halfx2 hv = *(const halfx2*)(hb + (size_t)s * NHD);
            ax += w * (float)hv.x;
            ay += w * (float)hv.y;
        }
        float inv = (deg > 0) ? 1.0f / sm : 0.0f;
        halfx2 o2;
        o2.x = (_Float16)(ax * inv);
        o2.y = (_Float16)(ay * inv);
        *(halfx2*)(out16 + (size_t)g * NHD + head * ND + l32 * 2) = o2;
    }
}

// ---------------- BatchNorm stats from f16 activations ----------------
// 128 thr/block: thread = channel pair; block adds into replica blk&7.
// Contention per address: 640/8 = 80 serialized adds (was 1280 in R6 -> 71 us).

__global__ __launch_bounds__(128) void bnreduce_kernel(const unsigned short* __restrict__ x16,
                                                       float* __restrict__ sums) {
    int tid = threadIdx.x;
    int c2 = tid * 2;
    float sx = 0.f, sx2 = 0.f, sy = 0.f, sy2 = 0.f;
    for (int row = blockIdx.x; row < ROWS; row += gridDim.x) {
        halfx2 hv = *(const halfx2*)(x16 + (size_t)row * NHD + c2);
        float vx = (float)hv.x, vy = (float)hv.y;
        sx += vx;
        sx2 += vx * vx;
        sy += vy;
        sy2 += vy * vy;
    }
    float* sr = sums + (blockIdx.x & (NREP - 1)) * 2 * NHD;
    atomicAdd(&sr[c2], sx);
    atomicAdd(&sr[c2 + 1], sy);
    atomicAdd(&sr[NHD + c2], sx2);
    atomicAdd(&sr[NHD + c2 + 1], sy2);
}

// ---------------- output head (inline BN+lrelu) + f16 window shift ----------------

__global__ __launch_bounds__(256) void headout_kernel(const unsigned short* __restrict__ x16,
                                                      const float* __restrict__ sums,
                                                      const float* __restrict__ gamma,
                                                      const float* __restrict__ beta,
                                                      const float* __restrict__ Wout,
                                                      const float* __restrict__ bout,
                                                      float* __restrict__ out,
                                                      unsigned short* __restrict__ xx16, int t) {
    __shared__ float bsc[NHD];
    __shared__ float bsh[NHD];
    {
        int c = threadIdx.x;
        float s = 0.0f, s2 = 0.0f;
#pragma unroll
        for (int r2 = 0; r2 < NREP; ++r2) {
            s += sums[r2 * 2 * NHD + c];
            s2 += sums[r2 * 2 * NHD + NHD + c];
        }
        const float invn = 1.0f / (float)ROWS;
        float mu = s * invn;
        float var = s2 * invn - mu * mu;
        float sc = rsqrtf(var + BNEPS) * gamma[c];
        bsc[c] = sc;
        bsh[c] = beta[c] - mu * sc;
    }
    __syncthreads();

    int wave = threadIdx.x >> 6;
    int lane = threadIdx.x & 63;
    int g = blockIdx.x * 4 + wave;
    int c0 = lane * 4;
    halfx4 hv = *(const halfx4*)(x16 + (size_t)g * NHD + c0);
    float vv[4];
#pragma unroll
    for (int j = 0; j < 4; ++j) {
        float x = fmaf((float)hv[j], bsc[c0 + j], bsh[c0 + j]);
        vv[j] = (x > 0.0f) ? x : 0.01f * x;
    }
    float r0 = vv[0] * Wout[(c0 + 0) * NOUT + 0] + vv[1] * Wout[(c0 + 1) * NOUT + 0] +
               vv[2] * Wout[(c0 + 2) * NOUT + 0] + vv[3] * Wout[(c0 + 3) * NOUT + 0];
    float r1 = vv[0] * Wout[(c0 + 0) * NOUT + 1] + vv[1] * Wout[(c0 + 1) * NOUT + 1] +
               vv[2] * Wout[(c0 + 2) * NOUT + 1] + vv[3] * Wout[(c0 + 3) * NOUT + 1];
    float r2 = vv[0] * Wout[(c0 + 0) * NOUT + 2] + vv[1] * Wout[(c0 + 1) * NOUT + 2] +
               vv[2] * Wout[(c0 + 2) * NOUT + 2] + vv[3] * Wout[(c0 + 3) * NOUT + 2];
#pragma unroll
    for (int o = 32; o; o >>= 1) {
        r0 += __shfl_xor(r0, o);
        r1 += __shfl_xor(r1, o);
        r2 += __shfl_xor(r2, o);
    }
    float o0 = r0 + bout[0], o1 = r1 + bout[1], o2 = r2 + bout[2];
    if (lane == 0) {
        float* op = out + ((size_t)g * NT + t) * NOUT;
        op[0] = o0;
        op[1] = o1;
        op[2] = o2;
    }
    // shift f16 input window: new[0:27] = old[3:30]; new[27:30] = out
    float oldv = (lane < NIN) ? h2f(xx16[(size_t)g * K0PAD + lane]) : 0.0f;
    float shifted = __shfl(oldv, lane + 3);
    float newv = (lane < 27) ? shifted : (lane == 27 ? o0 : (lane == 28 ? o1 : o2));
    if (lane < NIN) xx16[(size_t)g * K0PAD + lane] = f2h(newv);
}

// ---------------- launch ----------------

extern "C" void kernel_launch(void* const* d_in, const int* in_sizes, int n_in,
                              void* d_out, int out_size, void* d_ws, size_t ws_size,
                              hipStream_t stream) {
    const float* xx = (const float*)d_in[0];
    const int* src = (const int*)d_in[1];
    const int* dst = (const int*)d_in[2];
    const float* W[4] = {(const float*)d_in[3], (const float*)d_in[8],
                         (const float*)d_in[13], (const float*)d_in[18]};
    const float* al[4] = {(const float*)d_in[4], (const float*)d_in[9],
                          (const float*)d_in[14], (const float*)d_in[19]};
    const float* ar[4] = {(const float*)d_in[5], (const float*)d_in[10],
                          (const float*)d_in[15], (const float*)d_in[20]};
    const float* gamma[4] = {(const float*)d_in[6], (const float*)d_in[11],
                             (const float*)d_in[16], (const float*)d_in[21]};
    const float* beta[4] = {(const float*)d_in[7], (const float*)d_in[12],
                            (const float*)d_in[17], (const float*)d_in[22]};
    const float* W_out = (const float*)d_in[23];
    const float* b_out = (const float*)d_in[24];
    float* out = (float*)d_out;

    // workspace carve
    float* wsf = (float*)d_ws;
    float* el = wsf;                                        // ROWS*NH
    float* er = el + (size_t)ROWS * NH;                     // ROWS*NH
    float* sums = er + (size_t)ROWS * NH;                   // NREP*2*NHD
    unsigned short* h16 = (unsigned short*)(sums + NREP * 2 * NHD); // ROWS*NHD
    unsigned short* act16 = h16 + (size_t)ROWS * NHD;       // ROWS*NHD (attn out)
    unsigned short* xx16 = act16 + (size_t)ROWS * NHD;      // ROWS*K0PAD
    unsigned short* Wt0 = xx16 + (size_t)ROWS * K0PAD;      // 256*K0PAD
    unsigned short* Wt1 = Wt0 + 256 * K0PAD;                // 256*256
    unsigned short* Wt2 = Wt1 + 256 * NHD;
    unsigned short* Wt3 = Wt2 + 256 * NHD;
    int* counts = (int*)(Wt3 + 256 * NHD);                  // NNODES
    int* offsets = counts + NNODES;                         // NNODES+1 (+pad)
    int* cursor = offsets + NNODES + 8;                     // NNODES
    int* csr_src = cursor + NNODES;                         // NEDGES
    const unsigned short* Wt[4] = {Wt0, Wt1, Wt2, Wt3};

    // ---- CSR build + packing (once per launch) ----
    hipMemsetAsync(counts, 0, NNODES * sizeof(int), stream);
    count_kernel<<<(NEDGES + 255) / 256, 256, 0, stream>>>(dst, counts, NEDGES);
    scan_kernel<<<1, 1024, 0, stream>>>(counts, offsets, NNODES);
    hipMemsetAsync(cursor, 0, NNODES * sizeof(int), stream);
    fill_kernel<<<(NEDGES + 255) / 256, 256, 0, stream>>>(src, dst, offsets, cursor,
                                                          csr_src, NEDGES);
    pack_xx_kernel<<<(ROWS * K0PAD + 255) / 256, 256, 0, stream>>>(xx, xx16);
    packWt_kernel<<<256, 256, 0, stream>>>(W[0], Wt0, NIN, K0PAD);
    packWt_kernel<<<256, 256, 0, stream>>>(W[1], Wt1, NHD, NHD);
    packWt_kernel<<<256, 256, 0, stream>>>(W[2], Wt2, NHD, NHD);
    packWt_kernel<<<256, 256, 0, stream>>>(W[3], Wt3, NHD, NHD);

    for (int t = 0; t < NT; ++t) {
        for (int l = 0; l < 4; ++l) {
            const unsigned short* A16 = (l == 0) ? xx16 : act16;
            int K = (l == 0) ? K0PAD : NHD;
            int apply_bn = (l > 0) ? 1 : 0;
            const float* pg = gamma[(l > 0) ? l - 1 : 0];
            const float* pb = beta[(l > 0) ? l - 1 : 0];
            gemm_mfma_kernel<<<ROWS / 64, 256, 0, stream>>>(A16, Wt[l], al[l], ar[l],
                                                            sums, pg, pb, apply_bn,
                                                            h16, el, er, K);
            attn_kernel<<<ROWS / 2, 256, 0, stream>>>(h16, el, er, offsets, csr_src,
                                                      act16, sums);
            bnreduce_kernel<<<640, 128, 0, stream>>>(act16, sums);
        }
        headout_kernel<<<ROWS / 4, 256, 0, stream>>>(act16, sums, gamma[3], beta[3],
                                                     W_out, b_out, out, xx16, t);
    }
}

// Round 8
// 1909.184 us; speedup vs baseline: 1.5229x; 1.0079x over previous
//
#include <hip/hip_runtime.h>
#include <math.h>

#define NNODES 5000
#define NEDGES 80000
#define NB 8
#define NIN 30
#define K0PAD 32
#define NH 4
#define ND 64
#define NHD 256
#define NT 5
#define NOUT 3
#define ROWS (NB * NNODES) // 40000
#define BNEPS 1e-5f
#define KP 40   // LDS k-stride for A tile (shorts); 80B rows -> 2-way alias (free)
#define NREP 8  // sums[] replicas (atomic-contention spread)

#define GLOBAL_AS __attribute__((address_space(1)))
#define LDS_AS __attribute__((address_space(3)))

typedef short shortx8 __attribute__((ext_vector_type(8)));
typedef _Float16 halfx8 __attribute__((ext_vector_type(8)));
typedef _Float16 halfx4 __attribute__((ext_vector_type(4)));
typedef _Float16 halfx2 __attribute__((ext_vector_type(2)));
typedef float floatx4 __attribute__((ext_vector_type(4)));

static __device__ __forceinline__ unsigned short f2h(float f) {
    union { _Float16 h; unsigned short u; } v;
    v.h = (_Float16)f;
    return v.u;
}
static __device__ __forceinline__ float h2f(unsigned short u) {
    union { _Float16 h; unsigned short u; } v;
    v.u = u;
    return (float)v.h;
}

// ---------------- CSR build ----------------

__global__ void count_kernel(const int* __restrict__ dst, int* __restrict__ counts, int n) {
    int e = blockIdx.x * blockDim.x + threadIdx.x;
    if (e < n) atomicAdd(&counts[dst[e]], 1);
}

__global__ __launch_bounds__(1024) void scan_kernel(const int* __restrict__ counts,
                                                    int* __restrict__ offsets, int n) {
    __shared__ int smem[1024];
    const int CH = 5;
    int tid = threadIdx.x;
    int base = tid * CH;
    int loc[CH];
    int s = 0;
    for (int j = 0; j < CH; ++j) {
        int i = base + j;
        int v = (i < n) ? counts[i] : 0;
        loc[j] = s;
        s += v;
    }
    smem[tid] = s;
    __syncthreads();
    for (int off = 1; off < 1024; off <<= 1) {
        int v = (tid >= off) ? smem[tid - off] : 0;
        __syncthreads();
        smem[tid] += v;
        __syncthreads();
    }
    int excl = smem[tid] - s;
    for (int j = 0; j < CH; ++j) {
        int i = base + j;
        if (i < n) offsets[i] = excl + loc[j];
    }
    if (tid == 1023) offsets[n] = smem[1023];
}

__global__ void fill_kernel(const int* __restrict__ src, const int* __restrict__ dst,
                            const int* __restrict__ offsets, int* __restrict__ cursor,
                            int* __restrict__ csr_src, int n) {
    int e = blockIdx.x * blockDim.x + threadIdx.x;
    if (e >= n) return;
    int d = dst[e];
    int pos = offsets[d] + atomicAdd(&cursor[d], 1);
    csr_src[pos] = src[e];
}

// ---------------- packing ----------------

__global__ void pack_xx_kernel(const float* __restrict__ xx, unsigned short* __restrict__ xx16) {
    int idx = blockIdx.x * blockDim.x + threadIdx.x;
    if (idx >= ROWS * K0PAD) return;
    int g = idx >> 5;
    int k = idx & 31;
    float v = (k < NIN) ? xx[(size_t)g * NIN + k] : 0.0f;
    xx16[idx] = f2h(v);
}

// WtP: per 32-k tile, 16B chunks (n,quad) at swizzled pos p = n*4 + (quad ^ ((n>>1)&3)).
// chunk holds f16 Wt[n][t*32 + quad*8 .. +8]. Linear LDS image => global_load_lds-able;
// swizzle spreads ds_read_b128 fragment reads across banks.
__global__ void packWt_kernel(const float* __restrict__ W, unsigned short* __restrict__ WtP,
                              int Kin, int Kpad) {
    int n = blockIdx.x;
    int k = threadIdx.x;
    if (k < Kpad) {
        float v = (k < Kin) ? W[(size_t)k * NHD + n] : 0.0f;
        int t = k >> 5;
        int quad = (k >> 3) & 3;
        int j = k & 7;
        int p = n * 4 + (quad ^ ((n >> 1) & 3));
        WtP[(size_t)t * (NHD * 32) + p * 8 + j] = f2h(v);
    }
}

// ---------------- MFMA GEMM + fused BN(prev layer) on A + fused el/er ----------------
// B tile staged via global_load_lds (16B, DMA, no VGPR round-trip); A tile via VALU
// (BN+lrelu fold). Bs unpadded 256x32 with XOR-swizzled chunk layout (see packWt).

__global__ __launch_bounds__(256) void gemm_mfma_kernel(
    const unsigned short* __restrict__ A, const unsigned short* __restrict__ Wt,
    const float* __restrict__ alw, const float* __restrict__ arw,
    const float* __restrict__ sums, const float* __restrict__ gamma,
    const float* __restrict__ beta, int apply_bn,
    unsigned short* __restrict__ C16, float* __restrict__ el, float* __restrict__ er,
    int K) {
    __shared__ __align__(16) short As[64 * KP];
    __shared__ __align__(16) short Bs[256 * 32];
    __shared__ float bn_scale[NHD];
    __shared__ float bn_shift[NHD];
    int tid = threadIdx.x;
    if (apply_bn) {
        int c = tid;
        float s = 0.0f, s2 = 0.0f;
#pragma unroll
        for (int r2 = 0; r2 < NREP; ++r2) {
            s += sums[r2 * 2 * NHD + c];
            s2 += sums[r2 * 2 * NHD + NHD + c];
        }
        const float invn = 1.0f / (float)ROWS;
        float mu = s * invn;
        float var = s2 * invn - mu * mu;
        float sc = rsqrtf(var + BNEPS) * gamma[c];
        bn_scale[c] = sc;
        bn_shift[c] = beta[c] - mu * sc;
    }
    __syncthreads();

    int wave = tid >> 6; // head
    int lane = tid & 63;
    int c = lane & 15;
    int quad = lane >> 4;
    int xorv = (c >> 1) & 3;
    int row0 = blockIdx.x * 64;

    floatx4 acc[4][4];
#pragma unroll
    for (int mt = 0; mt < 4; ++mt)
#pragma unroll
        for (int nt = 0; nt < 4; ++nt) acc[mt][nt] = (floatx4){0.f, 0.f, 0.f, 0.f};

    int r = tid >> 2;
    int seg = tid & 3;
    for (int k0 = 0; k0 < K; k0 += 32) {
        // stage B tile (16 KB) via async DMA: 4 calls x 256 lanes x 16 B
        const unsigned short* gB = Wt + (size_t)(k0 >> 5) * (NHD * 32);
#pragma unroll
        for (int i = 0; i < 4; ++i) {
            int ci = i * 256 + tid;
            __builtin_amdgcn_global_load_lds(
                (const GLOBAL_AS unsigned int*)(gB + ci * 8),
                (LDS_AS unsigned int*)(&Bs[ci * 8]), 16, 0, 0);
        }
        // stage A tile 64x32 (+ fused BN + leakyrelu)
        {
            shortx8 v = *(const shortx8*)(A + (size_t)(row0 + r) * K + k0 + seg * 8);
            if (apply_bn) {
                halfx8 hv = *(halfx8*)&v;
                int kg = k0 + seg * 8;
#pragma unroll
                for (int j = 0; j < 8; ++j) {
                    float x = (float)hv[j];
                    x = fmaf(x, bn_scale[kg + j], bn_shift[kg + j]);
                    x = (x > 0.0f) ? x : 0.01f * x;
                    hv[j] = (_Float16)x;
                }
                v = *(shortx8*)&hv;
            }
            *(shortx8*)(&As[r * KP + seg * 8]) = v;
        }
        __syncthreads();
        halfx8 a[4], b[4];
#pragma unroll
        for (int mt = 0; mt < 4; ++mt)
            a[mt] = *(const halfx8*)(&As[(mt * 16 + c) * KP + quad * 8]);
#pragma unroll
        for (int nt = 0; nt < 4; ++nt) {
            int p = (wave * 64 + nt * 16 + c) * 4 + (quad ^ xorv);
            b[nt] = *(const halfx8*)(&Bs[p * 8]);
        }
#pragma unroll
        for (int mt = 0; mt < 4; ++mt)
#pragma unroll
            for (int nt = 0; nt < 4; ++nt)
                acc[mt][nt] = __builtin_amdgcn_mfma_f32_16x16x32_f16(a[mt], b[nt],
                                                                     acc[mt][nt], 0, 0, 0);
        __syncthreads();
    }

    // epilogue: store f16 C + fused el/er
    float alv[4], arv[4];
#pragma unroll
    for (int nt = 0; nt < 4; ++nt) {
        alv[nt] = alw[wave * 64 + nt * 16 + c];
        arv[nt] = arw[wave * 64 + nt * 16 + c];
    }
#pragma unroll
    for (int mt = 0; mt < 4; ++mt) {
#pragma unroll
        for (int rr = 0; rr < 4; ++rr) {
            int row = row0 + mt * 16 + quad * 4 + rr;
            float pl = 0.0f, pr = 0.0f;
#pragma unroll
            for (int nt = 0; nt < 4; ++nt) {
                float v = acc[mt][nt][rr];
                C16[(size_t)row * NHD + wave * 64 + nt * 16 + c] = f2h(v);
                pl += v * alv[nt];
                pr += v * arv[nt];
            }
#pragma unroll
            for (int o = 1; o < 16; o <<= 1) {
                pl += __shfl_xor(pl, o);
                pr += __shfl_xor(pr, o);
            }
            if (c == mt * 4 + rr) {
                el[(size_t)row * NH + wave] = pl;
                er[(size_t)row * NH + wave] = pr;
            }
        }
    }
}

// ---------------- edge softmax + aggregate ----------------
// Half-wave (32 lanes) = (node, head); 2 nodes/block. Logit phase: lane-per-edge.
// Gather phase: 2 edges/iter, 16 lanes per edge, halfx4 (8B) loads; weights/src
// broadcast via single per-lane-indexed shfl (halves bpermute + VMEM count vs R7).
// Block 0 zeroes all NREP sums replicas.

__global__ __launch_bounds__(256) void attn_kernel(const unsigned short* __restrict__ h16,
                                                   const float* __restrict__ el,
                                                   const float* __restrict__ er,
                                                   const int* __restrict__ offsets,
                                                   const int* __restrict__ csr_src,
                                                   unsigned short* __restrict__ out16,
                                                   float* __restrict__ sums) {
    int p = blockIdx.x;
    int tid = threadIdx.x;
    if (p == 0) {
        for (int i = tid; i < NREP * 2 * NHD; i += 256) sums[i] = 0.0f;
    }
    int b = p & 7;
    int n2 = p >> 3; // 0..2499
    int hw = tid >> 5;      // half-wave 0..7
    int nn = hw >> 2;       // node within pair
    int head = hw & 3;
    int l32 = tid & 31;
    int n = n2 * 2 + nn;
    int g = b * NNODES + n;
    int start = offsets[n];
    int end = offsets[n + 1];
    int deg = end - start;
    const float* elb = el + (size_t)b * NNODES * NH;
    float er_nh = er[(size_t)g * NH + head];

    if (deg <= 64) {
        // phase 1: lane i holds edge i (and i+32) src + softmax weight
        int s0 = 0, s1 = 0;
        float e0 = -INFINITY, e1 = -INFINITY;
        if (l32 < deg) {
            s0 = csr_src[start + l32];
            float e = elb[s0 * NH + head] + er_nh;
            e0 = (e > 0.0f) ? e : 0.2f * e;
        }
        if (l32 + 32 < deg) {
            s1 = csr_src[start + 32 + l32];
            float e = elb[s1 * NH + head] + er_nh;
            e1 = (e > 0.0f) ? e : 0.2f * e;
        }
        float mx = fmaxf(e0, e1);
#pragma unroll
        for (int o = 16; o; o >>= 1) mx = fmaxf(mx, __shfl_xor(mx, o));
        float w0 = __expf(e0 - mx);
        float w1 = __expf(e1 - mx);
        float sm = w0 + w1;
#pragma unroll
        for (int o = 16; o; o >>= 1) sm += __shfl_xor(sm, o);

        // phase 2: 16 lanes per edge, halfx4 channels, 2 edges per iteration
        int sub = l32 >> 4; // which of the 2 concurrent edges this lane serves
        int li = l32 & 15;  // channel quad within the head
        const unsigned short* hb4 = h16 + (size_t)b * NNODES * NHD + head * ND + li * 4;
        float a0 = 0.f, a1 = 0.f, a2 = 0.f, a3 = 0.f;
        int dlo = (deg < 32) ? deg : 32;
        for (int j = 0; j < dlo; j += 2) {
            int e = j + sub;
            bool valid = (e < dlo);
            int ec = valid ? e : (dlo - 1);
            int sa = __shfl(s0, ec, 32);
            float wa = __shfl(w0, ec, 32);
            wa = valid ? wa : 0.0f;
            halfx4 hv = *(const halfx4*)(hb4 + (size_t)sa * NHD);
            a0 += wa * (float)hv[0];
            a1 += wa * (float)hv[1];
            a2 += wa * (float)hv[2];
            a3 += wa * (float)hv[3];
        }
        for (int j = 32; j < deg; j += 2) {
            int e = j + sub;
            bool valid = (e < deg);
            int ec = valid ? (e - 32) : (deg - 33);
            int sa = __shfl(s1, ec, 32);
            float wa = __shfl(w1, ec, 32);
            wa = valid ? wa : 0.0f;
            halfx4 hv = *(const halfx4*)(hb4 + (size_t)sa * NHD);
            a0 += wa * (float)hv[0];
            a1 += wa * (float)hv[1];
            a2 += wa * (float)hv[2];
            a3 += wa * (float)hv[3];
        }
        // combine the two edge-subgroups (lane ^ 16 stays within the half-wave)
        a0 += __shfl_xor(a0, 16);
        a1 += __shfl_xor(a1, 16);
        a2 += __shfl_xor(a2, 16);
        a3 += __shfl_xor(a3, 16);
        if (sub == 0) {
            float inv = (deg > 0) ? 1.0f / sm : 0.0f;
            halfx4 o4;
            o4[0] = (_Float16)(a0 * inv);
            o4[1] = (_Float16)(a1 * inv);
            o4[2] = (_Float16)(a2 * inv);
            o4[3] = (_Float16)(a3 * inv);
            *(halfx4*)(out16 + (size_t)g * NHD + head * ND + li * 4) = o4;
        }
    } else {
        // fallback: 3-pass recompute from CSR (deg > 64, rare)
        const unsigned short* hb = h16 + (size_t)b * NNODES * NHD + head * ND + l32 * 2;
        float mx = -INFINITY;
        for (int i = start + l32; i < end; i += 32) {
            float e = elb[csr_src[i] * NH + head] + er_nh;
            e = (e > 0.0f) ? e : 0.2f * e;
            mx = fmaxf(mx, e);
        }
#pragma unroll
        for (int o = 16; o; o >>= 1) mx = fmaxf(mx, __shfl_xor(mx, o));
        float sm = 0.0f;
        for (int i = start + l32; i < end; i += 32) {
            float e = elb[csr_src[i] * NH + head] + er_nh;
            e = (e > 0.0f) ? e : 0.2f * e;
            sm += __expf(e - mx);
        }
#pragma unroll
        for (int o = 16; o; o >>= 1) sm += __shfl_xor(sm, o);
        float ax = 0.f, ay = 0.f;
        for (int i = start; i < end; ++i) {
            int s = csr_src[i];
            float e = elb[s * NH + head] + er_nh;
            e = (e > 0.0f) ? e : 0.2f * e;
            float w = __expf(e - mx);
            halfx2 hv = *(const halfx2*)(hb + (size_t)s * NHD);
            ax += w * (float)hv.x;
            ay += w * (float)hv.y;
        }
        float inv = (deg > 0) ? 1.0f / sm : 0.0f;
        halfx2 o2;
        o2.x = (_Float16)(ax * inv);
        o2.y = (_Float16)(ay * inv);
        *(halfx2*)(out16 + (size_t)g * NHD + head * ND + l32 * 2) = o2;
    }
}

// ---------------- BatchNorm stats from f16 activations ----------------
// 128 thr/block: thread = channel pair; block adds into replica blk&7.

__global__ __launch_bounds__(128) void bnreduce_kernel(const unsigned short* __restrict__ x16,
                                                       float* __restrict__ sums) {
    int tid = threadIdx.x;
    int c2 = tid * 2;
    float sx = 0.f, sx2 = 0.f, sy = 0.f, sy2 = 0.f;
    for (int row = blockIdx.x; row < ROWS; row += gridDim.x) {
        halfx2 hv = *(const halfx2*)(x16 + (size_t)row * NHD + c2);
        float vx = (float)hv.x, vy = (float)hv.y;
        sx += vx;
        sx2 += vx * vx;
        sy += vy;
        sy2 += vy * vy;
    }
    float* sr = sums + (blockIdx.x & (NREP - 1)) * 2 * NHD;
    atomicAdd(&sr[c2], sx);
    atomicAdd(&sr[c2 + 1], sy);
    atomicAdd(&sr[NHD + c2], sx2);
    atomicAdd(&sr[NHD + c2 + 1], sy2);
}

// ---------------- output head (inline BN+lrelu) + f16 window shift ----------------

__global__ __launch_bounds__(256) void headout_kernel(const unsigned short* __restrict__ x16,
                                                      const float* __restrict__ sums,
                                                      const float* __restrict__ gamma,
                                                      const float* __restrict__ beta,
                                                      const float* __restrict__ Wout,
                                                      const float* __restrict__ bout,
                                                      float* __restrict__ out,
                                                      unsigned short* __restrict__ xx16, int t) {
    __shared__ float bsc[NHD];
    __shared__ float bsh[NHD];
    {
        int c = threadIdx.x;
        float s = 0.0f, s2 = 0.0f;
#pragma unroll
        for (int r2 = 0; r2 < NREP; ++r2) {
            s += sums[r2 * 2 * NHD + c];
            s2 += sums[r2 * 2 * NHD + NHD + c];
        }
        const float invn = 1.0f / (float)ROWS;
        float mu = s * invn;
        float var = s2 * invn - mu * mu;
        float sc = rsqrtf(var + BNEPS) * gamma[c];
        bsc[c] = sc;
        bsh[c] = beta[c] - mu * sc;
    }
    __syncthreads();

    int wave = threadIdx.x >> 6;
    int lane = threadIdx.x & 63;
    int g = blockIdx.x * 4 + wave;
    int c0 = lane * 4;
    halfx4 hv = *(const halfx4*)(x16 + (size_t)g * NHD + c0);
    float vv[4];
#pragma unroll
    for (int j = 0; j < 4; ++j) {
        float x = fmaf((float)hv[j], bsc[c0 + j], bsh[c0 + j]);
        vv[j] = (x > 0.0f) ? x : 0.01f * x;
    }
    float r0 = vv[0] * Wout[(c0 + 0) * NOUT + 0] + vv[1] * Wout[(c0 + 1) * NOUT + 0] +
               vv[2] * Wout[(c0 + 2) * NOUT + 0] + vv[3] * Wout[(c0 + 3) * NOUT + 0];
    float r1 = vv[0] * Wout[(c0 + 0) * NOUT + 1] + vv[1] * Wout[(c0 + 1) * NOUT + 1] +
               vv[2] * Wout[(c0 + 2) * NOUT + 1] + vv[3] * Wout[(c0 + 3) * NOUT + 1];
    float r2 = vv[0] * Wout[(c0 + 0) * NOUT + 2] + vv[1] * Wout[(c0 + 1) * NOUT + 2] +
               vv[2] * Wout[(c0 + 2) * NOUT + 2] + vv[3] * Wout[(c0 + 3) * NOUT + 2];
#pragma unroll
    for (int o = 32; o; o >>= 1) {
        r0 += __shfl_xor(r0, o);
        r1 += __shfl_xor(r1, o);
        r2 += __shfl_xor(r2, o);
    }
    float o0 = r0 + bout[0], o1 = r1 + bout[1], o2 = r2 + bout[2];
    if (lane == 0) {
        float* op = out + ((size_t)g * NT + t) * NOUT;
        op[0] = o0;
        op[1] = o1;
        op[2] = o2;
    }
    // shift f16 input window: new[0:27] = old[3:30]; new[27:30] = out
    float oldv = (lane < NIN) ? h2f(xx16[(size_t)g * K0PAD + lane]) : 0.0f;
    float shifted = __shfl(oldv, lane + 3);
    float newv = (lane < 27) ? shifted : (lane == 27 ? o0 : (lane == 28 ? o1 : o2));
    if (lane < NIN) xx16[(size_t)g * K0PAD + lane] = f2h(newv);
}

// ---------------- launch ----------------

extern "C" void kernel_launch(void* const* d_in, const int* in_sizes, int n_in,
                              void* d_out, int out_size, void* d_ws, size_t ws_size,
                              hipStream_t stream) {
    const float* xx = (const float*)d_in[0];
    const int* src = (const int*)d_in[1];
    const int* dst = (const int*)d_in[2];
    const float* W[4] = {(const float*)d_in[3], (const float*)d_in[8],
                         (const float*)d_in[13], (const float*)d_in[18]};
    const float* al[4] = {(const float*)d_in[4], (const float*)d_in[9],
                          (const float*)d_in[14], (const float*)d_in[19]};
    const float* ar[4] = {(const float*)d_in[5], (const float*)d_in[10],
                          (const float*)d_in[15], (const float*)d_in[20]};
    const float* gamma[4] = {(const float*)d_in[6], (const float*)d_in[11],
                             (const float*)d_in[16], (const float*)d_in[21]};
    const float* beta[4] = {(const float*)d_in[7], (const float*)d_in[12],
                            (const float*)d_in[17], (const float*)d_in[22]};
    const float* W_out = (const float*)d_in[23];
    const float* b_out = (const float*)d_in[24];
    float* out = (float*)d_out;

    // workspace carve
    float* wsf = (float*)d_ws;
    float* el = wsf;                                        // ROWS*NH
    float* er = el + (size_t)ROWS * NH;                     // ROWS*NH
    float* sums = er + (size_t)ROWS * NH;                   // NREP*2*NHD
    unsigned short* h16 = (unsigned short*)(sums + NREP * 2 * NHD); // ROWS*NHD
    unsigned short* act16 = h16 + (size_t)ROWS * NHD;       // ROWS*NHD (attn out)
    unsigned short* xx16 = act16 + (size_t)ROWS * NHD;      // ROWS*K0PAD
    unsigned short* Wt0 = xx16 + (size_t)ROWS * K0PAD;      // 256*K0PAD
    unsigned short* Wt1 = Wt0 + 256 * K0PAD;                // 256*256
    unsigned short* Wt2 = Wt1 + 256 * NHD;
    unsigned short* Wt3 = Wt2 + 256 * NHD;
    int* counts = (int*)(Wt3 + 256 * NHD);                  // NNODES
    int* offsets = counts + NNODES;                         // NNODES+1 (+pad)
    int* cursor = offsets + NNODES + 8;                     // NNODES
    int* csr_src = cursor + NNODES;                         // NEDGES
    const unsigned short* Wt[4] = {Wt0, Wt1, Wt2, Wt3};

    // ---- CSR build + packing (once per launch) ----
    hipMemsetAsync(counts, 0, NNODES * sizeof(int), stream);
    count_kernel<<<(NEDGES + 255) / 256, 256, 0, stream>>>(dst, counts, NEDGES);
    scan_kernel<<<1, 1024, 0, stream>>>(counts, offsets, NNODES);
    hipMemsetAsync(cursor, 0, NNODES * sizeof(int), stream);
    fill_kernel<<<(NEDGES + 255) / 256, 256, 0, stream>>>(src, dst, offsets, cursor,
                                                          csr_src, NEDGES);
    pack_xx_kernel<<<(ROWS * K0PAD + 255) / 256, 256, 0, stream>>>(xx, xx16);
    packWt_kernel<<<256, 256, 0, stream>>>(W[0], (unsigned short*)Wt0, NIN, K0PAD);
    packWt_kernel<<<256, 256, 0, stream>>>(W[1], (unsigned short*)Wt1, NHD, NHD);
    packWt_kernel<<<256, 256, 0, stream>>>(W[2], (unsigned short*)Wt2, NHD, NHD);
    packWt_kernel<<<256, 256, 0, stream>>>(W[3], (unsigned short*)Wt3, NHD, NHD);

    for (int t = 0; t < NT; ++t) {
        for (int l = 0; l < 4; ++l) {
            const unsigned short* A16 = (l == 0) ? xx16 : act16;
            int K = (l == 0) ? K0PAD : NHD;
            int apply_bn = (l > 0) ? 1 : 0;
            const float* pg = gamma[(l > 0) ? l - 1 : 0];
            const float* pb = beta[(l > 0) ? l - 1 : 0];
            gemm_mfma_kernel<<<ROWS / 64, 256, 0, stream>>>(A16, Wt[l], al[l], ar[l],
                                                            sums, pg, pb, apply_bn,
                                                            h16, el, er, K);
            attn_kernel<<<ROWS / 2, 256, 0, stream>>>(h16, el, er, offsets, csr_src,
                                                      act16, sums);
            bnreduce_kernel<<<640, 128, 0, stream>>>(act16, sums);
        }
        headout_kernel<<<ROWS / 4, 256, 0, stream>>>(act16, sums, gamma[3], beta[3],
                                                     W_out, b_out, out, xx16, t);
    }
}

// Round 9
// 1647.995 us; speedup vs baseline: 1.7642x; 1.1585x over previous
//
#include <hip/hip_runtime.h>
#include <math.h>

#define NNODES 5000
#define NEDGES 80000
#define NB 8
#define NIN 30
#define K0PAD 32
#define NH 4
#define ND 64
#define NHD 256
#define NT 5
#define NOUT 3
#define ROWS (NB * NNODES) // 40000
#define BNEPS 1e-5f
#define KP 40   // LDS k-stride for A tile (shorts); 80B rows -> 2-way alias (free)
#define NREP 8  // sums[] replicas (atomic-contention spread)

#define GLOBAL_AS __attribute__((address_space(1)))
#define LDS_AS __attribute__((address_space(3)))

typedef short shortx8 __attribute__((ext_vector_type(8)));
typedef _Float16 halfx8 __attribute__((ext_vector_type(8)));
typedef _Float16 halfx4 __attribute__((ext_vector_type(4)));
typedef _Float16 halfx2 __attribute__((ext_vector_type(2)));
typedef float floatx4 __attribute__((ext_vector_type(4)));

static __device__ __forceinline__ unsigned short f2h(float f) {
    union { _Float16 h; unsigned short u; } v;
    v.h = (_Float16)f;
    return v.u;
}
static __device__ __forceinline__ float h2f(unsigned short u) {
    union { _Float16 h; unsigned short u; } v;
    v.u = u;
    return (float)v.h;
}

// ---------------- CSR build ----------------

__global__ void count_kernel(const int* __restrict__ dst, int* __restrict__ counts, int n) {
    int e = blockIdx.x * blockDim.x + threadIdx.x;
    if (e < n) atomicAdd(&counts[dst[e]], 1);
}

__global__ __launch_bounds__(1024) void scan_kernel(const int* __restrict__ counts,
                                                    int* __restrict__ offsets, int n) {
    __shared__ int smem[1024];
    const int CH = 5;
    int tid = threadIdx.x;
    int base = tid * CH;
    int loc[CH];
    int s = 0;
    for (int j = 0; j < CH; ++j) {
        int i = base + j;
        int v = (i < n) ? counts[i] : 0;
        loc[j] = s;
        s += v;
    }
    smem[tid] = s;
    __syncthreads();
    for (int off = 1; off < 1024; off <<= 1) {
        int v = (tid >= off) ? smem[tid - off] : 0;
        __syncthreads();
        smem[tid] += v;
        __syncthreads();
    }
    int excl = smem[tid] - s;
    for (int j = 0; j < CH; ++j) {
        int i = base + j;
        if (i < n) offsets[i] = excl + loc[j];
    }
    if (tid == 1023) offsets[n] = smem[1023];
}

__global__ void fill_kernel(const int* __restrict__ src, const int* __restrict__ dst,
                            const int* __restrict__ offsets, int* __restrict__ cursor,
                            int* __restrict__ csr_src, int n) {
    int e = blockIdx.x * blockDim.x + threadIdx.x;
    if (e >= n) return;
    int d = dst[e];
    int pos = offsets[d] + atomicAdd(&cursor[d], 1);
    csr_src[pos] = src[e];
}

// ---------------- packing ----------------

__global__ void pack_xx_kernel(const float* __restrict__ xx, unsigned short* __restrict__ xx16) {
    int idx = blockIdx.x * blockDim.x + threadIdx.x;
    if (idx >= ROWS * K0PAD) return;
    int g = idx >> 5;
    int k = idx & 31;
    float v = (k < NIN) ? xx[(size_t)g * NIN + k] : 0.0f;
    xx16[idx] = f2h(v);
}

// WtP: per 32-k tile, 16B chunks (n,quad) at swizzled pos p = n*4 + (quad ^ ((n>>1)&3)).
__global__ void packWt_kernel(const float* __restrict__ W, unsigned short* __restrict__ WtP,
                              int Kin, int Kpad) {
    int n = blockIdx.x;
    int k = threadIdx.x;
    if (k < Kpad) {
        float v = (k < Kin) ? W[(size_t)k * NHD + n] : 0.0f;
        int t = k >> 5;
        int quad = (k >> 3) & 3;
        int j = k & 7;
        int p = n * 4 + (quad ^ ((n >> 1) & 3));
        WtP[(size_t)t * (NHD * 32) + p * 8 + j] = f2h(v);
    }
}

// ---------------- MFMA GEMM + fused BN(prev layer) on A + fused el/er ----------------
// B tile staged via global_load_lds (16B DMA); A tile via VALU (BN+lrelu fold).

__global__ __launch_bounds__(256) void gemm_mfma_kernel(
    const unsigned short* __restrict__ A, const unsigned short* __restrict__ Wt,
    const float* __restrict__ alw, const float* __restrict__ arw,
    const float* __restrict__ sums, const float* __restrict__ gamma,
    const float* __restrict__ beta, int apply_bn,
    unsigned short* __restrict__ C16, float* __restrict__ el, float* __restrict__ er,
    int K) {
    __shared__ __align__(16) short As[64 * KP];
    __shared__ __align__(16) short Bs[256 * 32];
    __shared__ float bn_scale[NHD];
    __shared__ float bn_shift[NHD];
    int tid = threadIdx.x;
    if (apply_bn) {
        int c = tid;
        float s = 0.0f, s2 = 0.0f;
#pragma unroll
        for (int r2 = 0; r2 < NREP; ++r2) {
            s += sums[r2 * 2 * NHD + c];
            s2 += sums[r2 * 2 * NHD + NHD + c];
        }
        const float invn = 1.0f / (float)ROWS;
        float mu = s * invn;
        float var = s2 * invn - mu * mu;
        float sc = rsqrtf(var + BNEPS) * gamma[c];
        bn_scale[c] = sc;
        bn_shift[c] = beta[c] - mu * sc;
    }
    __syncthreads();

    int wave = tid >> 6; // head
    int lane = tid & 63;
    int c = lane & 15;
    int quad = lane >> 4;
    int xorv = (c >> 1) & 3;
    int row0 = blockIdx.x * 64;

    floatx4 acc[4][4];
#pragma unroll
    for (int mt = 0; mt < 4; ++mt)
#pragma unroll
        for (int nt = 0; nt < 4; ++nt) acc[mt][nt] = (floatx4){0.f, 0.f, 0.f, 0.f};

    int r = tid >> 2;
    int seg = tid & 3;
    for (int k0 = 0; k0 < K; k0 += 32) {
        const unsigned short* gB = Wt + (size_t)(k0 >> 5) * (NHD * 32);
#pragma unroll
        for (int i = 0; i < 4; ++i) {
            int ci = i * 256 + tid;
            __builtin_amdgcn_global_load_lds(
                (const GLOBAL_AS unsigned int*)(gB + ci * 8),
                (LDS_AS unsigned int*)(&Bs[ci * 8]), 16, 0, 0);
        }
        {
            shortx8 v = *(const shortx8*)(A + (size_t)(row0 + r) * K + k0 + seg * 8);
            if (apply_bn) {
                halfx8 hv = *(halfx8*)&v;
                int kg = k0 + seg * 8;
#pragma unroll
                for (int j = 0; j < 8; ++j) {
                    float x = (float)hv[j];
                    x = fmaf(x, bn_scale[kg + j], bn_shift[kg + j]);
                    x = (x > 0.0f) ? x : 0.01f * x;
                    hv[j] = (_Float16)x;
                }
                v = *(shortx8*)&hv;
            }
            *(shortx8*)(&As[r * KP + seg * 8]) = v;
        }
        __syncthreads();
        halfx8 a[4], b[4];
#pragma unroll
        for (int mt = 0; mt < 4; ++mt)
            a[mt] = *(const halfx8*)(&As[(mt * 16 + c) * KP + quad * 8]);
#pragma unroll
        for (int nt = 0; nt < 4; ++nt) {
            int pq = (wave * 64 + nt * 16 + c) * 4 + (quad ^ xorv);
            b[nt] = *(const halfx8*)(&Bs[pq * 8]);
        }
#pragma unroll
        for (int mt = 0; mt < 4; ++mt)
#pragma unroll
            for (int nt = 0; nt < 4; ++nt)
                acc[mt][nt] = __builtin_amdgcn_mfma_f32_16x16x32_f16(a[mt], b[nt],
                                                                     acc[mt][nt], 0, 0, 0);
        __syncthreads();
    }

    float alv[4], arv[4];
#pragma unroll
    for (int nt = 0; nt < 4; ++nt) {
        alv[nt] = alw[wave * 64 + nt * 16 + c];
        arv[nt] = arw[wave * 64 + nt * 16 + c];
    }
#pragma unroll
    for (int mt = 0; mt < 4; ++mt) {
#pragma unroll
        for (int rr = 0; rr < 4; ++rr) {
            int row = row0 + mt * 16 + quad * 4 + rr;
            float pl = 0.0f, pr = 0.0f;
#pragma unroll
            for (int nt = 0; nt < 4; ++nt) {
                float v = acc[mt][nt][rr];
                C16[(size_t)row * NHD + wave * 64 + nt * 16 + c] = f2h(v);
                pl += v * alv[nt];
                pr += v * arv[nt];
            }
#pragma unroll
            for (int o = 1; o < 16; o <<= 1) {
                pl += __shfl_xor(pl, o);
                pr += __shfl_xor(pr, o);
            }
            if (c == mt * 4 + rr) {
                el[(size_t)row * NH + wave] = pl;
                er[(size_t)row * NH + wave] = pr;
            }
        }
    }
}

// ---------------- edge softmax + aggregate: WAVE PER NODE ----------------
// Lane layout: head = lane>>4, li = lane&15. Phase 1 done once per node
// (was 4x redundant across half-waves). Gather: per edge the full wave loads
// the neighbor's 256 channels as one contiguous 512B row (halfx4 @ lane*4);
// weight selected per-head via one bpermute. Unroll x2 for load ILP.
// Block 0 zeroes all NREP sums replicas.

__global__ __launch_bounds__(256) void attn_kernel(const unsigned short* __restrict__ h16,
                                                   const float* __restrict__ el,
                                                   const float* __restrict__ er,
                                                   const int* __restrict__ offsets,
                                                   const int* __restrict__ csr_src,
                                                   unsigned short* __restrict__ out16,
                                                   float* __restrict__ sums) {
    int p = blockIdx.x;
    int tid = threadIdx.x;
    if (p == 0) {
        for (int i = tid; i < NREP * 2 * NHD; i += 256) sums[i] = 0.0f;
    }
    int b = p & 7;
    int wave = tid >> 6;
    int lane = tid & 63;
    int head = lane >> 4;
    int li = lane & 15;
    int n = ((p >> 3) << 2) + wave;
    int g = b * NNODES + n;
    int start = offsets[n];
    int deg = offsets[n + 1] - start;
    unsigned short* outp = out16 + (size_t)g * NHD + lane * 4;
    if (deg == 0) {
        *(unsigned long long*)outp = 0ULL;
        return;
    }
    const float* elb = el + (size_t)b * NNODES * NH;
    float er_nh = er[(size_t)g * NH + head];
    const unsigned short* hbase = h16 + (size_t)b * NNODES * NHD + lane * 4;

    if (deg <= 64) {
        // phase 1: lane li of each head-group owns edges li+16k
        float e[4], w[4];
        int s[4];
#pragma unroll
        for (int k = 0; k < 4; ++k) {
            int idx = k * 16 + li;
            if (idx < deg) {
                s[k] = csr_src[start + idx];
                float t = elb[s[k] * NH + head] + er_nh;
                e[k] = (t > 0.0f) ? t : 0.2f * t;
            } else {
                s[k] = 0;
                e[k] = -INFINITY;
            }
        }
        float mx = fmaxf(fmaxf(e[0], e[1]), fmaxf(e[2], e[3]));
#pragma unroll
        for (int o = 8; o; o >>= 1) mx = fmaxf(mx, __shfl_xor(mx, o));
        float sm = 0.0f;
#pragma unroll
        for (int k = 0; k < 4; ++k) {
            w[k] = __expf(e[k] - mx); // exp(-inf)=0 pads invalid slots
            sm += w[k];
        }
#pragma unroll
        for (int o = 8; o; o >>= 1) sm += __shfl_xor(sm, o);

        // phase 2: one 512B coalesced row per edge; per-head weight via bpermute
        float a0 = 0.f, a1 = 0.f, a2 = 0.f, a3 = 0.f;
        int hsel = lane & 48;
#define GATHER_CHUNK(K)                                                         \
        if (deg > (K) * 16) {                                                   \
            int cnt = deg - (K) * 16;                                           \
            cnt = (cnt > 16) ? 16 : cnt;                                        \
            int j = 0;                                                          \
            for (; j + 2 <= cnt; j += 2) {                                      \
                int sa = __shfl(s[K], j);                                       \
                float wa = __shfl(w[K], hsel + j);                              \
                int sb2 = __shfl(s[K], j + 1);                                  \
                float wb = __shfl(w[K], hsel + j + 1);                          \
                halfx4 ha = *(const halfx4*)(hbase + (size_t)sa * NHD);         \
                halfx4 hb2 = *(const halfx4*)(hbase + (size_t)sb2 * NHD);       \
                a0 += wa * (float)ha[0]; a1 += wa * (float)ha[1];               \
                a2 += wa * (float)ha[2]; a3 += wa * (float)ha[3];               \
                a0 += wb * (float)hb2[0]; a1 += wb * (float)hb2[1];             \
                a2 += wb * (float)hb2[2]; a3 += wb * (float)hb2[3];             \
            }                                                                   \
            if (j < cnt) {                                                      \
                int sa = __shfl(s[K], j);                                       \
                float wa = __shfl(w[K], hsel + j);                              \
                halfx4 ha = *(const halfx4*)(hbase + (size_t)sa * NHD);         \
                a0 += wa * (float)ha[0]; a1 += wa * (float)ha[1];               \
                a2 += wa * (float)ha[2]; a3 += wa * (float)ha[3];               \
            }                                                                   \
        }
        GATHER_CHUNK(0)
        GATHER_CHUNK(1)
        GATHER_CHUNK(2)
        GATHER_CHUNK(3)
#undef GATHER_CHUNK
        float inv = 1.0f / sm;
        halfx4 o4;
        o4[0] = (_Float16)(a0 * inv);
        o4[1] = (_Float16)(a1 * inv);
        o4[2] = (_Float16)(a2 * inv);
        o4[3] = (_Float16)(a3 * inv);
        *(halfx4*)outp = o4;
    } else {
        // generic fallback (deg > 64, rare): strided logits + recompute gather
        float mx = -INFINITY;
        for (int i = li; i < deg; i += 16) {
            int s2 = csr_src[start + i];
            float t = elb[s2 * NH + head] + er_nh;
            t = (t > 0.0f) ? t : 0.2f * t;
            mx = fmaxf(mx, t);
        }
#pragma unroll
        for (int o = 8; o; o >>= 1) mx = fmaxf(mx, __shfl_xor(mx, o));
        float sm = 0.0f;
        for (int i = li; i < deg; i += 16) {
            int s2 = csr_src[start + i];
            float t = elb[s2 * NH + head] + er_nh;
            t = (t > 0.0f) ? t : 0.2f * t;
            sm += __expf(t - mx);
        }
#pragma unroll
        for (int o = 8; o; o >>= 1) sm += __shfl_xor(sm, o);
        float a0 = 0.f, a1 = 0.f, a2 = 0.f, a3 = 0.f;
        for (int j = 0; j < deg; ++j) {
            int s2 = csr_src[start + j]; // uniform address -> broadcast
            float t = elb[s2 * NH + head] + er_nh;
            t = (t > 0.0f) ? t : 0.2f * t;
            float wj = __expf(t - mx);
            halfx4 hv = *(const halfx4*)(hbase + (size_t)s2 * NHD);
            a0 += wj * (float)hv[0];
            a1 += wj * (float)hv[1];
            a2 += wj * (float)hv[2];
            a3 += wj * (float)hv[3];
        }
        float inv = 1.0f / sm;
        halfx4 o4;
        o4[0] = (_Float16)(a0 * inv);
        o4[1] = (_Float16)(a1 * inv);
        o4[2] = (_Float16)(a2 * inv);
        o4[3] = (_Float16)(a3 * inv);
        *(halfx4*)outp = o4;
    }
}

// ---------------- BatchNorm stats from f16 activations ----------------

__global__ __launch_bounds__(128) void bnreduce_kernel(const unsigned short* __restrict__ x16,
                                                       float* __restrict__ sums) {
    int tid = threadIdx.x;
    int c2 = tid * 2;
    float sx = 0.f, sx2 = 0.f, sy = 0.f, sy2 = 0.f;
    for (int row = blockIdx.x; row < ROWS; row += gridDim.x) {
        halfx2 hv = *(const halfx2*)(x16 + (size_t)row * NHD + c2);
        float vx = (float)hv.x, vy = (float)hv.y;
        sx += vx;
        sx2 += vx * vx;
        sy += vy;
        sy2 += vy * vy;
    }
    float* sr = sums + (blockIdx.x & (NREP - 1)) * 2 * NHD;
    atomicAdd(&sr[c2], sx);
    atomicAdd(&sr[c2 + 1], sy);
    atomicAdd(&sr[NHD + c2], sx2);
    atomicAdd(&sr[NHD + c2 + 1], sy2);
}

// ---------------- output head (inline BN+lrelu) + f16 window shift ----------------

__global__ __launch_bounds__(256) void headout_kernel(const unsigned short* __restrict__ x16,
                                                      const float* __restrict__ sums,
                                                      const float* __restrict__ gamma,
                                                      const float* __restrict__ beta,
                                                      const float* __restrict__ Wout,
                                                      const float* __restrict__ bout,
                                                      float* __restrict__ out,
                                                      unsigned short* __restrict__ xx16, int t) {
    __shared__ float bsc[NHD];
    __shared__ float bsh[NHD];
    {
        int c = threadIdx.x;
        float s = 0.0f, s2 = 0.0f;
#pragma unroll
        for (int r2 = 0; r2 < NREP; ++r2) {
            s += sums[r2 * 2 * NHD + c];
            s2 += sums[r2 * 2 * NHD + NHD + c];
        }
        const float invn = 1.0f / (float)ROWS;
        float mu = s * invn;
        float var = s2 * invn - mu * mu;
        float sc = rsqrtf(var + BNEPS) * gamma[c];
        bsc[c] = sc;
        bsh[c] = beta[c] - mu * sc;
    }
    __syncthreads();

    int wave = threadIdx.x >> 6;
    int lane = threadIdx.x & 63;
    int g = blockIdx.x * 4 + wave;
    int c0 = lane * 4;
    halfx4 hv = *(const halfx4*)(x16 + (size_t)g * NHD + c0);
    float vv[4];
#pragma unroll
    for (int j = 0; j < 4; ++j) {
        float x = fmaf((float)hv[j], bsc[c0 + j], bsh[c0 + j]);
        vv[j] = (x > 0.0f) ? x : 0.01f * x;
    }
    float r0 = vv[0] * Wout[(c0 + 0) * NOUT + 0] + vv[1] * Wout[(c0 + 1) * NOUT + 0] +
               vv[2] * Wout[(c0 + 2) * NOUT + 0] + vv[3] * Wout[(c0 + 3) * NOUT + 0];
    float r1 = vv[0] * Wout[(c0 + 0) * NOUT + 1] + vv[1] * Wout[(c0 + 1) * NOUT + 1] +
               vv[2] * Wout[(c0 + 2) * NOUT + 1] + vv[3] * Wout[(c0 + 3) * NOUT + 1];
    float r2 = vv[0] * Wout[(c0 + 0) * NOUT + 2] + vv[1] * Wout[(c0 + 1) * NOUT + 2] +
               vv[2] * Wout[(c0 + 2) * NOUT + 2] + vv[3] * Wout[(c0 + 3) * NOUT + 2];
#pragma unroll
    for (int o = 32; o; o >>= 1) {
        r0 += __shfl_xor(r0, o);
        r1 += __shfl_xor(r1, o);
        r2 += __shfl_xor(r2, o);
    }
    float o0 = r0 + bout[0], o1 = r1 + bout[1], o2 = r2 + bout[2];
    if (lane == 0) {
        float* op = out + ((size_t)g * NT + t) * NOUT;
        op[0] = o0;
        op[1] = o1;
        op[2] = o2;
    }
    float oldv = (lane < NIN) ? h2f(xx16[(size_t)g * K0PAD + lane]) : 0.0f;
    float shifted = __shfl(oldv, lane + 3);
    float newv = (lane < 27) ? shifted : (lane == 27 ? o0 : (lane == 28 ? o1 : o2));
    if (lane < NIN) xx16[(size_t)g * K0PAD + lane] = f2h(newv);
}

// ---------------- launch ----------------

extern "C" void kernel_launch(void* const* d_in, const int* in_sizes, int n_in,
                              void* d_out, int out_size, void* d_ws, size_t ws_size,
                              hipStream_t stream) {
    const float* xx = (const float*)d_in[0];
    const int* src = (const int*)d_in[1];
    const int* dst = (const int*)d_in[2];
    const float* W[4] = {(const float*)d_in[3], (const float*)d_in[8],
                         (const float*)d_in[13], (const float*)d_in[18]};
    const float* al[4] = {(const float*)d_in[4], (const float*)d_in[9],
                          (const float*)d_in[14], (const float*)d_in[19]};
    const float* ar[4] = {(const float*)d_in[5], (const float*)d_in[10],
                          (const float*)d_in[15], (const float*)d_in[20]};
    const float* gamma[4] = {(const float*)d_in[6], (const float*)d_in[11],
                             (const float*)d_in[16], (const float*)d_in[21]};
    const float* beta[4] = {(const float*)d_in[7], (const float*)d_in[12],
                            (const float*)d_in[17], (const float*)d_in[22]};
    const float* W_out = (const float*)d_in[23];
    const float* b_out = (const float*)d_in[24];
    float* out = (float*)d_out;

    // workspace carve
    float* wsf = (float*)d_ws;
    float* el = wsf;                                        // ROWS*NH
    float* er = el + (size_t)ROWS * NH;                     // ROWS*NH
    float* sums = er + (size_t)ROWS * NH;                   // NREP*2*NHD
    unsigned short* h16 = (unsigned short*)(sums + NREP * 2 * NHD); // ROWS*NHD
    unsigned short* act16 = h16 + (size_t)ROWS * NHD;       // ROWS*NHD (attn out)
    unsigned short* xx16 = act16 + (size_t)ROWS * NHD;      // ROWS*K0PAD
    unsigned short* Wt0 = xx16 + (size_t)ROWS * K0PAD;      // 256*K0PAD
    unsigned short* Wt1 = Wt0 + 256 * K0PAD;                // 256*256
    unsigned short* Wt2 = Wt1 + 256 * NHD;
    unsigned short* Wt3 = Wt2 + 256 * NHD;
    int* counts = (int*)(Wt3 + 256 * NHD);                  // NNODES
    int* offsets = counts + NNODES;                         // NNODES+1 (+pad)
    int* cursor = offsets + NNODES + 8;                     // NNODES
    int* csr_src = cursor + NNODES;                         // NEDGES
    const unsigned short* Wt[4] = {Wt0, Wt1, Wt2, Wt3};

    // ---- CSR build + packing (once per launch) ----
    hipMemsetAsync(counts, 0, NNODES * sizeof(int), stream);
    count_kernel<<<(NEDGES + 255) / 256, 256, 0, stream>>>(dst, counts, NEDGES);
    scan_kernel<<<1, 1024, 0, stream>>>(counts, offsets, NNODES);
    hipMemsetAsync(cursor, 0, NNODES * sizeof(int), stream);
    fill_kernel<<<(NEDGES + 255) / 256, 256, 0, stream>>>(src, dst, offsets, cursor,
                                                          csr_src, NEDGES);
    pack_xx_kernel<<<(ROWS * K0PAD + 255) / 256, 256, 0, stream>>>(xx, xx16);
    packWt_kernel<<<256, 256, 0, stream>>>(W[0], (unsigned short*)Wt0, NIN, K0PAD);
    packWt_kernel<<<256, 256, 0, stream>>>(W[1], (unsigned short*)Wt1, NHD, NHD);
    packWt_kernel<<<256, 256, 0, stream>>>(W[2], (unsigned short*)Wt2, NHD, NHD);
    packWt_kernel<<<256, 256, 0, stream>>>(W[3], (unsigned short*)Wt3, NHD, NHD);

    for (int t = 0; t < NT; ++t) {
        for (int l = 0; l < 4; ++l) {
            const unsigned short* A16 = (l == 0) ? xx16 : act16;
            int K = (l == 0) ? K0PAD : NHD;
            int apply_bn = (l > 0) ? 1 : 0;
            const float* pg = gamma[(l > 0) ? l - 1 : 0];
            const float* pb = beta[(l > 0) ? l - 1 : 0];
            gemm_mfma_kernel<<<ROWS / 64, 256, 0, stream>>>(A16, Wt[l], al[l], ar[l],
                                                            sums, pg, pb, apply_bn,
                                                            h16, el, er, K);
            attn_kernel<<<ROWS / 4, 256, 0, stream>>>(h16, el, er, offsets, csr_src,
                                                      act16, sums);
            bnreduce_kernel<<<640, 128, 0, stream>>>(act16, sums);
        }
        headout_kernel<<<ROWS / 4, 256, 0, stream>>>(act16, sums, gamma[3], beta[3],
                                                     W_out, b_out, out, xx16, t);
    }
}

// Round 11
// 1510.868 us; speedup vs baseline: 1.9244x; 1.0908x over previous
//
#include <hip/hip_runtime.h>
#include <math.h>

#define NNODES 5000
#define NEDGES 80000
#define NB 8
#define NIN 30
#define K0PAD 32
#define NH 4
#define ND 64
#define NHD 256
#define NT 5
#define NOUT 3
#define ROWS (NB * NNODES) // 40000
#define BNEPS 1e-5f
#define KP 40   // LDS k-stride for A tile (shorts); 80B rows -> 2-way alias (free)
#define NREP 8  // sums[] replicas (atomic-contention spread)
#define BM 32   // gemm M-tile (32 -> 1250 blocks, 4.9/CU co-residency)

#define GLOBAL_AS __attribute__((address_space(1)))
#define LDS_AS __attribute__((address_space(3)))

typedef short shortx8 __attribute__((ext_vector_type(8)));
typedef _Float16 halfx8 __attribute__((ext_vector_type(8)));
typedef _Float16 halfx4 __attribute__((ext_vector_type(4)));
typedef _Float16 halfx2 __attribute__((ext_vector_type(2)));
typedef float floatx4 __attribute__((ext_vector_type(4)));

static __device__ __forceinline__ unsigned short f2h(float f) {
    union { _Float16 h; unsigned short u; } v;
    v.h = (_Float16)f;
    return v.u;
}
static __device__ __forceinline__ float h2f(unsigned short u) {
    union { _Float16 h; unsigned short u; } v;
    v.u = u;
    return (float)v.h;
}

// ---------------- CSR build ----------------

__global__ void count_kernel(const int* __restrict__ dst, int* __restrict__ counts, int n) {
    int e = blockIdx.x * blockDim.x + threadIdx.x;
    if (e < n) atomicAdd(&counts[dst[e]], 1);
}

__global__ __launch_bounds__(1024) void scan_kernel(const int* __restrict__ counts,
                                                    int* __restrict__ offsets, int n) {
    __shared__ int smem[1024];
    const int CH = 5;
    int tid = threadIdx.x;
    int base = tid * CH;
    int loc[CH];
    int s = 0;
    for (int j = 0; j < CH; ++j) {
        int i = base + j;
        int v = (i < n) ? counts[i] : 0;
        loc[j] = s;
        s += v;
    }
    smem[tid] = s;
    __syncthreads();
    for (int off = 1; off < 1024; off <<= 1) {
        int v = (tid >= off) ? smem[tid - off] : 0;
        __syncthreads();
        smem[tid] += v;
        __syncthreads();
    }
    int excl = smem[tid] - s;
    for (int j = 0; j < CH; ++j) {
        int i = base + j;
        if (i < n) offsets[i] = excl + loc[j];
    }
    if (tid == 1023) offsets[n] = smem[1023];
}

__global__ void fill_kernel(const int* __restrict__ src, const int* __restrict__ dst,
                            const int* __restrict__ offsets, int* __restrict__ cursor,
                            int* __restrict__ csr_src, int n) {
    int e = blockIdx.x * blockDim.x + threadIdx.x;
    if (e >= n) return;
    int d = dst[e];
    int pos = offsets[d] + atomicAdd(&cursor[d], 1);
    csr_src[pos] = src[e];
}

// ---------------- packing ----------------

__global__ void pack_xx_kernel(const float* __restrict__ xx, unsigned short* __restrict__ xx16) {
    int idx = blockIdx.x * blockDim.x + threadIdx.x;
    if (idx >= ROWS * K0PAD) return;
    int g = idx >> 5;
    int k = idx & 31;
    float v = (k < NIN) ? xx[(size_t)g * NIN + k] : 0.0f;
    xx16[idx] = f2h(v);
}

// WtP: per 32-k tile, 16B chunks (n,quad) at swizzled pos p = n*4 + (quad ^ ((n>>1)&3)).
// All 4 layers in one dispatch (blockIdx.y = layer).
__global__ void packWt_kernel(const float* __restrict__ W0, const float* __restrict__ W1,
                              const float* __restrict__ W2, const float* __restrict__ W3,
                              unsigned short* __restrict__ P0, unsigned short* __restrict__ P1,
                              unsigned short* __restrict__ P2, unsigned short* __restrict__ P3) {
    int l = blockIdx.y;
    const float* W = (l == 0) ? W0 : (l == 1) ? W1 : (l == 2) ? W2 : W3;
    unsigned short* WtP = (l == 0) ? P0 : (l == 1) ? P1 : (l == 2) ? P2 : P3;
    int Kin = (l == 0) ? NIN : NHD;
    int Kpad = (l == 0) ? K0PAD : NHD;
    int n = blockIdx.x;
    int k = threadIdx.x;
    if (k < Kpad) {
        float v = (k < Kin) ? W[(size_t)k * NHD + n] : 0.0f;
        int t = k >> 5;
        int quad = (k >> 3) & 3;
        int j = k & 7;
        int p = n * 4 + (quad ^ ((n >> 1) & 3));
        WtP[(size_t)t * (NHD * 32) + p * 8 + j] = f2h(v);
    }
}

// ---------------- MFMA GEMM + fused BN(prev layer) on A + fused el/er ----------------
// BM=32 rows/block (1250 blocks -> ~5/CU for latency hiding). B tile via
// global_load_lds 16B DMA; A tile via VALU (BN+lrelu fold).

__global__ __launch_bounds__(256) void gemm_mfma_kernel(
    const unsigned short* __restrict__ A, const unsigned short* __restrict__ Wt,
    const float* __restrict__ alw, const float* __restrict__ arw,
    const float* __restrict__ sums, const float* __restrict__ gamma,
    const float* __restrict__ beta, int apply_bn,
    unsigned short* __restrict__ C16, float* __restrict__ el, float* __restrict__ er,
    int K) {
    __shared__ __align__(16) short As[BM * KP];
    __shared__ __align__(16) short Bs[256 * 32];
    __shared__ float bn_scale[NHD];
    __shared__ float bn_shift[NHD];
    int tid = threadIdx.x;
    if (apply_bn) {
        int c = tid;
        float s = 0.0f, s2 = 0.0f;
#pragma unroll
        for (int r2 = 0; r2 < NREP; ++r2) {
            s += sums[r2 * 2 * NHD + c];
            s2 += sums[r2 * 2 * NHD + NHD + c];
        }
        const float invn = 1.0f / (float)ROWS;
        float mu = s * invn;
        float var = s2 * invn - mu * mu;
        float sc = rsqrtf(var + BNEPS) * gamma[c];
        bn_scale[c] = sc;
        bn_shift[c] = beta[c] - mu * sc;
    }
    __syncthreads();

    int wave = tid >> 6; // head
    int lane = tid & 63;
    int c = lane & 15;
    int quad = lane >> 4;
    int xorv = (c >> 1) & 3;
    int row0 = blockIdx.x * BM;

    floatx4 acc[2][4];
#pragma unroll
    for (int mt = 0; mt < 2; ++mt)
#pragma unroll
        for (int nt = 0; nt < 4; ++nt) acc[mt][nt] = (floatx4){0.f, 0.f, 0.f, 0.f};

    int r = tid >> 2;   // 0..63 (only <BM used)
    int seg = tid & 3;
    for (int k0 = 0; k0 < K; k0 += 32) {
        const unsigned short* gB = Wt + (size_t)(k0 >> 5) * (NHD * 32);
#pragma unroll
        for (int i = 0; i < 4; ++i) {
            int ci = i * 256 + tid;
            __builtin_amdgcn_global_load_lds(
                (const GLOBAL_AS unsigned int*)(gB + ci * 8),
                (LDS_AS unsigned int*)(&Bs[ci * 8]), 16, 0, 0);
        }
        if (r < BM) {
            shortx8 v = *(const shortx8*)(A + (size_t)(row0 + r) * K + k0 + seg * 8);
            if (apply_bn) {
                halfx8 hv = *(halfx8*)&v;
                int kg = k0 + seg * 8;
#pragma unroll
                for (int j = 0; j < 8; ++j) {
                    float x = (float)hv[j];
                    x = fmaf(x, bn_scale[kg + j], bn_shift[kg + j]);
                    x = (x > 0.0f) ? x : 0.01f * x;
                    hv[j] = (_Float16)x;
                }
                v = *(shortx8*)&hv;
            }
            *(shortx8*)(&As[r * KP + seg * 8]) = v;
        }
        __syncthreads();
        halfx8 a[2], b[4];
#pragma unroll
        for (int mt = 0; mt < 2; ++mt)
            a[mt] = *(const halfx8*)(&As[(mt * 16 + c) * KP + quad * 8]);
#pragma unroll
        for (int nt = 0; nt < 4; ++nt) {
            int pq = (wave * 64 + nt * 16 + c) * 4 + (quad ^ xorv);
            b[nt] = *(const halfx8*)(&Bs[pq * 8]);
        }
#pragma unroll
        for (int mt = 0; mt < 2; ++mt)
#pragma unroll
            for (int nt = 0; nt < 4; ++nt)
                acc[mt][nt] = __builtin_amdgcn_mfma_f32_16x16x32_f16(a[mt], b[nt],
                                                                     acc[mt][nt], 0, 0, 0);
        __syncthreads();
    }

    float alv[4], arv[4];
#pragma unroll
    for (int nt = 0; nt < 4; ++nt) {
        alv[nt] = alw[wave * 64 + nt * 16 + c];
        arv[nt] = arw[wave * 64 + nt * 16 + c];
    }
#pragma unroll
    for (int mt = 0; mt < 2; ++mt) {
#pragma unroll
        for (int rr = 0; rr < 4; ++rr) {
            int row = row0 + mt * 16 + quad * 4 + rr;
            float pl = 0.0f, pr = 0.0f;
#pragma unroll
            for (int nt = 0; nt < 4; ++nt) {
                float v = acc[mt][nt][rr];
                C16[(size_t)row * NHD + wave * 64 + nt * 16 + c] = f2h(v);
                pl += v * alv[nt];
                pr += v * arv[nt];
            }
#pragma unroll
            for (int o = 1; o < 16; o <<= 1) {
                pl += __shfl_xor(pl, o);
                pr += __shfl_xor(pr, o);
            }
            if (c == mt * 4 + rr) {
                el[(size_t)row * NH + wave] = pl;
                er[(size_t)row * NH + wave] = pr;
            }
        }
    }
}

// ---------------- edge softmax + aggregate: WAVE PER NODE ----------------
// Phase 1: head = lane>>4, li = lane&15 — logits once per node.
// Phase 2: lanes 0-31 load edge j's full 512B row as halfx8@i32*8; lanes 32-63
// load edge j+1 -> per 2 edges: 1 coalesced 16B load/lane + 2 bpermutes.
// R10 BUG FIX: phase-2 lane's channels belong to head i32>>3, but its own sm
// is for head lane>>4 -> fetch the right denominator via __shfl(sm, hsel).
// Block 0 zeroes all NREP sums replicas.

__global__ __launch_bounds__(256) void attn_kernel(const unsigned short* __restrict__ h16,
                                                   const float* __restrict__ el,
                                                   const float* __restrict__ er,
                                                   const int* __restrict__ offsets,
                                                   const int* __restrict__ csr_src,
                                                   unsigned short* __restrict__ out16,
                                                   float* __restrict__ sums) {
    int p = blockIdx.x;
    int tid = threadIdx.x;
    if (p == 0) {
        for (int i = tid; i < NREP * 2 * NHD; i += 256) sums[i] = 0.0f;
    }
    int b = p & 7;
    int wave = tid >> 6;
    int lane = tid & 63;
    int head = lane >> 4;
    int li = lane & 15;
    int n = ((p >> 3) << 2) + wave;
    int g = b * NNODES + n;
    int start = offsets[n];
    int deg = offsets[n + 1] - start;
    if (deg == 0) {
        *(unsigned long long*)(out16 + (size_t)g * NHD + lane * 4) = 0ULL;
        return;
    }
    const float* elb = el + (size_t)b * NNODES * NH;
    float er_nh = er[(size_t)g * NH + head];

    if (deg <= 64) {
        // phase 1: lane li of each head-group owns edges li+16k
        float e[4], w[4];
        int s[4];
#pragma unroll
        for (int k = 0; k < 4; ++k) {
            int idx = k * 16 + li;
            if (idx < deg) {
                s[k] = csr_src[start + idx];
                float t = elb[s[k] * NH + head] + er_nh;
                e[k] = (t > 0.0f) ? t : 0.2f * t;
            } else {
                s[k] = 0;
                e[k] = -INFINITY;
            }
        }
        float mx = fmaxf(fmaxf(e[0], e[1]), fmaxf(e[2], e[3]));
#pragma unroll
        for (int o = 8; o; o >>= 1) mx = fmaxf(mx, __shfl_xor(mx, o));
        float sm = 0.0f;
#pragma unroll
        for (int k = 0; k < 4; ++k) {
            w[k] = __expf(e[k] - mx); // exp(-inf)=0 pads invalid slots
            sm += w[k];
        }
#pragma unroll
        for (int o = 8; o; o >>= 1) sm += __shfl_xor(sm, o);

        // phase 2: sub = lane>>5 serves edges j+sub; i32 = lane&31 -> 8 channels
        int sub = lane >> 5;
        int i32 = lane & 31;
        int hsel = (lane & 24) << 1; // channel head (i32>>3) * 16
        float smh = __shfl(sm, hsel); // denominator for the CHANNEL head (R10 fix)
        const unsigned short* hrow = h16 + (size_t)b * NNODES * NHD + i32 * 8;
        float a0 = 0.f, a1 = 0.f, a2 = 0.f, a3 = 0.f;
        float a4 = 0.f, a5 = 0.f, a6 = 0.f, a7 = 0.f;
#define GATHER_CHUNK(K)                                                          \
        if (deg > (K) * 16) {                                                    \
            int cnt = deg - (K) * 16;                                            \
            cnt = (cnt > 16) ? 16 : cnt;                                         \
            int j = 0;                                                           \
            for (; j + 4 <= cnt; j += 4) {                                       \
                int sa = __shfl(s[K], j + sub);                                  \
                float wa = __shfl(w[K], hsel + j + sub);                         \
                int sb = __shfl(s[K], j + 2 + sub);                              \
                float wb = __shfl(w[K], hsel + j + 2 + sub);                     \
                halfx8 ha = *(const halfx8*)(hrow + (size_t)sa * NHD);           \
                halfx8 hb = *(const halfx8*)(hrow + (size_t)sb * NHD);           \
                a0 += wa * (float)ha[0]; a1 += wa * (float)ha[1];                \
                a2 += wa * (float)ha[2]; a3 += wa * (float)ha[3];                \
                a4 += wa * (float)ha[4]; a5 += wa * (float)ha[5];                \
                a6 += wa * (float)ha[6]; a7 += wa * (float)ha[7];                \
                a0 += wb * (float)hb[0]; a1 += wb * (float)hb[1];                \
                a2 += wb * (float)hb[2]; a3 += wb * (float)hb[3];                \
                a4 += wb * (float)hb[4]; a5 += wb * (float)hb[5];                \
                a6 += wb * (float)hb[6]; a7 += wb * (float)hb[7];                \
            }                                                                    \
            for (; j < cnt; j += 2) {                                            \
                int e2 = j + sub;                                                \
                bool valid = (e2 < cnt);                                         \
                int ec = valid ? e2 : (cnt - 1);                                 \
                int sa = __shfl(s[K], ec);                                       \
                float wa0 = __shfl(w[K], hsel + ec);                             \
                float wa = valid ? wa0 : 0.0f;                                   \
                halfx8 ha = *(const halfx8*)(hrow + (size_t)sa * NHD);           \
                a0 += wa * (float)ha[0]; a1 += wa * (float)ha[1];                \
                a2 += wa * (float)ha[2]; a3 += wa * (float)ha[3];                \
                a4 += wa * (float)ha[4]; a5 += wa * (float)ha[5];                \
                a6 += wa * (float)ha[6]; a7 += wa * (float)ha[7];                \
            }                                                                    \
        }
        GATHER_CHUNK(0)
        GATHER_CHUNK(1)
        GATHER_CHUNK(2)
        GATHER_CHUNK(3)
#undef GATHER_CHUNK
        a0 += __shfl_xor(a0, 32); a1 += __shfl_xor(a1, 32);
        a2 += __shfl_xor(a2, 32); a3 += __shfl_xor(a3, 32);
        a4 += __shfl_xor(a4, 32); a5 += __shfl_xor(a5, 32);
        a6 += __shfl_xor(a6, 32); a7 += __shfl_xor(a7, 32);
        if (sub == 0) {
            float inv = 1.0f / smh;
            halfx8 o8;
            o8[0] = (_Float16)(a0 * inv); o8[1] = (_Float16)(a1 * inv);
            o8[2] = (_Float16)(a2 * inv); o8[3] = (_Float16)(a3 * inv);
            o8[4] = (_Float16)(a4 * inv); o8[5] = (_Float16)(a5 * inv);
            o8[6] = (_Float16)(a6 * inv); o8[7] = (_Float16)(a7 * inv);
            *(halfx8*)(out16 + (size_t)g * NHD + i32 * 8) = o8;
        }
    } else {
        // generic fallback (deg > 64, rare)
        const unsigned short* hbase = h16 + (size_t)b * NNODES * NHD + lane * 4;
        float mx = -INFINITY;
        for (int i = li; i < deg; i += 16) {
            int s2 = csr_src[start + i];
            float t = elb[s2 * NH + head] + er_nh;
            t = (t > 0.0f) ? t : 0.2f * t;
            mx = fmaxf(mx, t);
        }
#pragma unroll
        for (int o = 8; o; o >>= 1) mx = fmaxf(mx, __shfl_xor(mx, o));
        float sm = 0.0f;
        for (int i = li; i < deg; i += 16) {
            int s2 = csr_src[start + i];
            float t = elb[s2 * NH + head] + er_nh;
            t = (t > 0.0f) ? t : 0.2f * t;
            sm += __expf(t - mx);
        }
#pragma unroll
        for (int o = 8; o; o >>= 1) sm += __shfl_xor(sm, o);
        float a0 = 0.f, a1 = 0.f, a2 = 0.f, a3 = 0.f;
        for (int j = 0; j < deg; ++j) {
            int s2 = csr_src[start + j];
            float t = elb[s2 * NH + head] + er_nh;
            t = (t > 0.0f) ? t : 0.2f * t;
            float wj = __expf(t - mx);
            halfx4 hv = *(const halfx4*)(hbase + (size_t)s2 * NHD);
            a0 += wj * (float)hv[0];
            a1 += wj * (float)hv[1];
            a2 += wj * (float)hv[2];
            a3 += wj * (float)hv[3];
        }
        float inv = 1.0f / sm;
        halfx4 o4;
        o4[0] = (_Float16)(a0 * inv);
        o4[1] = (_Float16)(a1 * inv);
        o4[2] = (_Float16)(a2 * inv);
        o4[3] = (_Float16)(a3 * inv);
        *(halfx4*)(out16 + (size_t)g * NHD + lane * 4) = o4;
    }
}

// ---------------- BatchNorm stats from f16 activations ----------------

__global__ __launch_bounds__(128) void bnreduce_kernel(const unsigned short* __restrict__ x16,
                                                       float* __restrict__ sums) {
    int tid = threadIdx.x;
    int c2 = tid * 2;
    float sx = 0.f, sx2 = 0.f, sy = 0.f, sy2 = 0.f;
    for (int row = blockIdx.x; row < ROWS; row += gridDim.x) {
        halfx2 hv = *(const halfx2*)(x16 + (size_t)row * NHD + c2);
        float vx = (float)hv.x, vy = (float)hv.y;
        sx += vx;
        sx2 += vx * vx;
        sy += vy;
        sy2 += vy * vy;
    }
    float* sr = sums + (blockIdx.x & (NREP - 1)) * 2 * NHD;
    atomicAdd(&sr[c2], sx);
    atomicAdd(&sr[c2 + 1], sy);
    atomicAdd(&sr[NHD + c2], sx2);
    atomicAdd(&sr[NHD + c2 + 1], sy2);
}

// ---------------- output head (inline BN+lrelu) + f16 window shift ----------------

__global__ __launch_bounds__(256) void headout_kernel(const unsigned short* __restrict__ x16,
                                                      const float* __restrict__ sums,
                                                      const float* __restrict__ gamma,
                                                      const float* __restrict__ beta,
                                                      const float* __restrict__ Wout,
                                                      const float* __restrict__ bout,
                                                      float* __restrict__ out,
                                                      unsigned short* __restrict__ xx16, int t) {
    __shared__ float bsc[NHD];
    __shared__ float bsh[NHD];
    {
        int c = threadIdx.x;
        float s = 0.0f, s2 = 0.0f;
#pragma unroll
        for (int r2 = 0; r2 < NREP; ++r2) {
            s += sums[r2 * 2 * NHD + c];
            s2 += sums[r2 * 2 * NHD + NHD + c];
        }
        const float invn = 1.0f / (float)ROWS;
        float mu = s * invn;
        float var = s2 * invn - mu * mu;
        float sc = rsqrtf(var + BNEPS) * gamma[c];
        bsc[c] = sc;
        bsh[c] = beta[c] - mu * sc;
    }
    __syncthreads();

    int wave = threadIdx.x >> 6;
    int lane = threadIdx.x & 63;
    int g = blockIdx.x * 4 + wave;
    int c0 = lane * 4;
    halfx4 hv = *(const halfx4*)(x16 + (size_t)g * NHD + c0);
    float vv[4];
#pragma unroll
    for (int j = 0; j < 4; ++j) {
        float x = fmaf((float)hv[j], bsc[c0 + j], bsh[c0 + j]);
        vv[j] = (x > 0.0f) ? x : 0.01f * x;
    }
    float r0 = vv[0] * Wout[(c0 + 0) * NOUT + 0] + vv[1] * Wout[(c0 + 1) * NOUT + 0] +
               vv[2] * Wout[(c0 + 2) * NOUT + 0] + vv[3] * Wout[(c0 + 3) * NOUT + 0];
    float r1 = vv[0] * Wout[(c0 + 0) * NOUT + 1] + vv[1] * Wout[(c0 + 1) * NOUT + 1] +
               vv[2] * Wout[(c0 + 2) * NOUT + 1] + vv[3] * Wout[(c0 + 3) * NOUT + 1];
    float r2 = vv[0] * Wout[(c0 + 0) * NOUT + 2] + vv[1] * Wout[(c0 + 1) * NOUT + 2] +
               vv[2] * Wout[(c0 + 2) * NOUT + 2] + vv[3] * Wout[(c0 + 3) * NOUT + 2];
#pragma unroll
    for (int o = 32; o; o >>= 1) {
        r0 += __shfl_xor(r0, o);
        r1 += __shfl_xor(r1, o);
        r2 += __shfl_xor(r2, o);
    }
    float o0 = r0 + bout[0], o1 = r1 + bout[1], o2 = r2 + bout[2];
    if (lane == 0) {
        float* op = out + ((size_t)g * NT + t) * NOUT;
        op[0] = o0;
        op[1] = o1;
        op[2] = o2;
    }
    float oldv = (lane < NIN) ? h2f(xx16[(size_t)g * K0PAD + lane]) : 0.0f;
    float shifted = __shfl(oldv, lane + 3);
    float newv = (lane < 27) ? shifted : (lane == 27 ? o0 : (lane == 28 ? o1 : o2));
    if (lane < NIN) xx16[(size_t)g * K0PAD + lane] = f2h(newv);
}

// ---------------- launch ----------------

extern "C" void kernel_launch(void* const* d_in, const int* in_sizes, int n_in,
                              void* d_out, int out_size, void* d_ws, size_t ws_size,
                              hipStream_t stream) {
    const float* xx = (const float*)d_in[0];
    const int* src = (const int*)d_in[1];
    const int* dst = (const int*)d_in[2];
    const float* W[4] = {(const float*)d_in[3], (const float*)d_in[8],
                         (const float*)d_in[13], (const float*)d_in[18]};
    const float* al[4] = {(const float*)d_in[4], (const float*)d_in[9],
                          (const float*)d_in[14], (const float*)d_in[19]};
    const float* ar[4] = {(const float*)d_in[5], (const float*)d_in[10],
                          (const float*)d_in[15], (const float*)d_in[20]};
    const float* gamma[4] = {(const float*)d_in[6], (const float*)d_in[11],
                             (const float*)d_in[16], (const float*)d_in[21]};
    const float* beta[4] = {(const float*)d_in[7], (const float*)d_in[12],
                            (const float*)d_in[17], (const float*)d_in[22]};
    const float* W_out = (const float*)d_in[23];
    const float* b_out = (const float*)d_in[24];
    float* out = (float*)d_out;

    // workspace carve
    float* wsf = (float*)d_ws;
    float* el = wsf;                                        // ROWS*NH
    float* er = el + (size_t)ROWS * NH;                     // ROWS*NH
    float* sums = er + (size_t)ROWS * NH;                   // NREP*2*NHD
    unsigned short* h16 = (unsigned short*)(sums + NREP * 2 * NHD); // ROWS*NHD
    unsigned short* act16 = h16 + (size_t)ROWS * NHD;       // ROWS*NHD (attn out)
    unsigned short* xx16 = act16 + (size_t)ROWS * NHD;      // ROWS*K0PAD
    unsigned short* Wt0 = xx16 + (size_t)ROWS * K0PAD;      // 256*K0PAD
    unsigned short* Wt1 = Wt0 + 256 * K0PAD;                // 256*256
    unsigned short* Wt2 = Wt1 + 256 * NHD;
    unsigned short* Wt3 = Wt2 + 256 * NHD;
    int* counts = (int*)(Wt3 + 256 * NHD);                  // NNODES
    int* offsets = counts + NNODES;                         // NNODES+1 (+pad)
    int* cursor = offsets + NNODES + 8;                     // NNODES
    int* csr_src = cursor + NNODES;                         // NEDGES
    const unsigned short* Wt[4] = {Wt0, Wt1, Wt2, Wt3};

    // ---- CSR build + packing (once per launch) ----
    hipMemsetAsync(counts, 0, NNODES * sizeof(int), stream);
    count_kernel<<<(NEDGES + 255) / 256, 256, 0, stream>>>(dst, counts, NEDGES);
    scan_kernel<<<1, 1024, 0, stream>>>(counts, offsets, NNODES);
    hipMemsetAsync(cursor, 0, NNODES * sizeof(int), stream);
    fill_kernel<<<(NEDGES + 255) / 256, 256, 0, stream>>>(src, dst, offsets, cursor,
                                                          csr_src, NEDGES);
    pack_xx_kernel<<<(ROWS * K0PAD + 255) / 256, 256, 0, stream>>>(xx, xx16);
    packWt_kernel<<<dim3(256, 4), 256, 0, stream>>>(W[0], W[1], W[2], W[3],
                                                    (unsigned short*)Wt0,
                                                    (unsigned short*)Wt1,
                                                    (unsigned short*)Wt2,
                                                    (unsigned short*)Wt3);

    for (int t = 0; t < NT; ++t) {
        for (int l = 0; l < 4; ++l) {
            const unsigned short* A16 = (l == 0) ? xx16 : act16;
            int K = (l == 0) ? K0PAD : NHD;
            int apply_bn = (l > 0) ? 1 : 0;
            const float* pg = gamma[(l > 0) ? l - 1 : 0];
            const float* pb = beta[(l > 0) ? l - 1 : 0];
            gemm_mfma_kernel<<<ROWS / BM, 256, 0, stream>>>(A16, Wt[l], al[l], ar[l],
                                                            sums, pg, pb, apply_bn,
                                                            h16, el, er, K);
            attn_kernel<<<ROWS / 4, 256, 0, stream>>>(h16, el, er, offsets, csr_src,
                                                      act16, sums);
            bnreduce_kernel<<<640, 128, 0, stream>>>(act16, sums);
        }
        headout_kernel<<<ROWS / 4, 256, 0, stream>>>(act16, sums, gamma[3], beta[3],
                                                     W_out, b_out, out, xx16, t);
    }
}